// Round 10
// baseline (293.305 us; speedup 1.0000x reference)
//
#include <hip/hip_runtime.h>
#include <hip/hip_bf16.h>
#include <math.h>

#define BB 64
#define NN 256
#define CCH 512

typedef unsigned short u16;
typedef __attribute__((ext_vector_type(8))) short s16x8;
typedef __attribute__((ext_vector_type(4))) float f32x4;

#define AS1 __attribute__((address_space(1)))
#define AS3 __attribute__((address_space(3)))

static __device__ __forceinline__ u16 f2b(float f) {
    __hip_bfloat16 h = __float2bfloat16(f);
    union { __hip_bfloat16 h; u16 u; } x; x.h = h; return x.u;
}
static __device__ __forceinline__ void gll16(const void* g, void* l) {
    __builtin_amdgcn_global_load_lds((const AS1 unsigned int*)g,
                                     (AS3 unsigned int*)l, 16, 0, 0);
}
static __device__ __forceinline__ int shf(int ni) {
    return (ni < 86) ? -1 : (ni < 172 ? 0 : 1);
}

#define VM8  asm volatile("s_waitcnt vmcnt(8)" ::: "memory")
#define VM6  asm volatile("s_waitcnt vmcnt(6)" ::: "memory")
#define VM0  asm volatile("s_waitcnt vmcnt(0)" ::: "memory")
#define LGKM0 asm volatile("s_waitcnt lgkmcnt(0)" ::: "memory")
#define MEMB asm volatile("" ::: "memory")

// ---- device-scope grid barrier (all 256 blocks co-resident: 1 block/CU) ----
static __device__ __forceinline__ void gbar(unsigned* bar, unsigned target)
{
    __syncthreads();                       // drains each wave's vmem/lds
    if (threadIdx.x == 0) {
        __threadfence();                   // release: L2 writeback
        __hip_atomic_fetch_add(bar, 1u, __ATOMIC_ACQ_REL, __HIP_MEMORY_SCOPE_AGENT);
        unsigned spins = 0;
        while (__hip_atomic_load(bar, __ATOMIC_ACQUIRE, __HIP_MEMORY_SCOPE_AGENT) < target) {
            __builtin_amdgcn_s_sleep(2);
            if (++spins > 4000000u) break; // escape valve: fail visibly, never hang
        }
        __threadfence();                   // acquire: cache invalidate
    }
    __syncthreads();
}

// ---------------- phase 0 helpers ----------------
// k-permutation: stored location = (k & ~63) | ((k&15)<<2) | ((k>>4)&3)
static __device__ __forceinline__ void wtc_body(const float* __restrict__ W,
    u16* __restrict__ Wt, int K, int N, int bx, int by, float* t, bool perm, int t2)
{
    int n0 = bx * 32, k0 = by * 32;
    int tx = t2 & 31, ty = t2 >> 5;
    #pragma unroll
    for (int i = 0; i < 4; ++i)
        t[(ty + i * 8) * 33 + tx] = W[(size_t)(k0 + ty + i * 8) * N + n0 + tx];
    __syncthreads();
    int kl = k0 + tx;
    int kp = perm ? ((kl & ~63) | ((kl & 15) << 2) | ((kl >> 4) & 3)) : kl;
    #pragma unroll
    for (int i = 0; i < 4; ++i)
        Wt[(size_t)(n0 + ty + i * 8) * K + kp] = f2b(t[tx * 33 + ty + i * 8]);
}

// ---------------- 6-slot pipelined GEMM phase (modes 0, 2, 3; BN=128) ----------------
// 64x64 wave tiles (4Mx2N), pi-permuted ushort4 epilogue stores.
template<int MODE>
static __device__ void gemm_phase(
    const u16* __restrict__ A, const u16* __restrict__ Bt,
    const float* __restrict__ bias, const float* __restrict__ res,
    void* __restrict__ outv, u16* __restrict__ auxout,
    float* __restrict__ SEpart, char* ldsraw, const int bid, const int tid)
{
    constexpr int NK = (MODE == 2) ? 32 : (MODE == 3) ? 24 : 16;
    constexpr int SA = (MODE == 2) ? 1024 : 512;
    constexpr int SB = (MODE == 2) ? 1024 : 512;

    u16* Asm = (u16*)ldsraw;              // 6*8192 u16 = 96KB
    u16* Bsm = (u16*)(ldsraw + 98304);    // 6*4096 u16 = 48KB

    const int l = tid & 63;
    const int w = tid >> 6;
    const int work = (bid & 7) * 32 + (bid >> 3);

    int row0, col0, bidx = 0;
    if (MODE == 0)      { row0 = (work >> 7) * 256; col0 = (work & 127) * 128; }
    else if (MODE == 2) { row0 = (work >> 2) * 256; col0 = (work & 3) * 128; }
    else                { row0 = 0; bidx = work >> 2; col0 = (work & 3) * 128; }

    const u16* Aab  = A + (size_t)row0 * SA;
    const u16* Bab  = Bt + (size_t)col0 * SB;
    const u16* HtsB = Bt + (size_t)bidx * 514 * 256;

    const int wm = (w >> 1) * 64;
    const int wn = (w & 1) * 64;
    const int fr = l & 15;
    const int q  = l >> 4;
    const int kofs = ((q ^ ((l >> 1) & 3)) * 8);

    const f32x4 zero = {0.0f, 0.0f, 0.0f, 0.0f};
    f32x4 acc[4][4];
    #pragma unroll
    for (int m = 0; m < 4; ++m)
        #pragma unroll
        for (int n = 0; n < 4; ++n) acc[m][n] = zero;

    const int kc0 = ((tid & 3) ^ ((tid >> 3) & 3)) * 8;
    const int srow = tid >> 2;

    auto stage = [&](int u, int slot) {
        u16* ald = Asm + slot * 8192 + w * 512;
        u16* bld = Bsm + slot * 4096 + w * 512;
        if (MODE == 3) {
            const int kseg = u >> 3, kb = (u & 7) * 32 + kc0;
            gll16(A + kseg * 65536 + srow * 256 + kb, ald);
            gll16(A + kseg * 65536 + (srow + 128) * 256 + kb, ald + 4096);
            gll16(HtsB + (size_t)(col0 + srow + kseg) * 256 + kb, bld);
        } else {
            const int kb = u * 32 + kc0;
            gll16(Aab + (size_t)srow * SA + kb, ald);
            gll16(Aab + (size_t)(srow + 128) * SA + kb, ald + 4096);
            gll16(Bab + (size_t)srow * SB + kb, bld);
        }
    };

    stage(0, 0); stage(1, 1); stage(2, 2); stage(3, 3);
    int sa = 0;
    constexpr int NV = NK / 2;
    for (int v = 0; v < NV; ++v) {
        if (v + 1 < NV) { VM6; } else { VM0; }
        __builtin_amdgcn_s_barrier();
        MEMB;
        const int sb = sa + 1;
        s16x8 b0[4], af0[4];
        #pragma unroll
        for (int n = 0; n < 4; ++n)
            b0[n] = *(const s16x8*)&Bsm[sa * 4096 + (wn + n * 16 + fr) * 32 + kofs];
        #pragma unroll
        for (int m = 0; m < 4; ++m)
            af0[m] = *(const s16x8*)&Asm[sa * 8192 + (wm + m * 16 + fr) * 32 + kofs];
        const int u2 = 2 * v + 4;
        if (u2 < NK) {
            int st = sa + 4; if (st >= 6) st -= 6;
            stage(u2, st);
            int st1 = st + 1; if (st1 >= 6) st1 -= 6;
            stage(u2 + 1, st1);
        }
        __builtin_amdgcn_s_setprio(1);
        #pragma unroll
        for (int m = 0; m < 4; ++m)
            #pragma unroll
            for (int n = 0; n < 4; ++n)
                acc[m][n] = __builtin_amdgcn_mfma_f32_16x16x32_bf16(af0[m], b0[n], acc[m][n], 0, 0, 0);
        __builtin_amdgcn_s_setprio(0);
        s16x8 b1[4], af1[4];
        #pragma unroll
        for (int n = 0; n < 4; ++n)
            b1[n] = *(const s16x8*)&Bsm[sb * 4096 + (wn + n * 16 + fr) * 32 + kofs];
        #pragma unroll
        for (int m = 0; m < 4; ++m)
            af1[m] = *(const s16x8*)&Asm[sb * 8192 + (wm + m * 16 + fr) * 32 + kofs];
        __builtin_amdgcn_s_setprio(1);
        #pragma unroll
        for (int m = 0; m < 4; ++m)
            #pragma unroll
            for (int n = 0; n < 4; ++n)
                acc[m][n] = __builtin_amdgcn_mfma_f32_16x16x32_bf16(af1[m], b1[n], acc[m][n], 0, 0, 0);
        __builtin_amdgcn_s_setprio(0);
        MEMB;
        sa += 2; if (sa >= 6) sa = 0;
    }

    if (MODE == 0) {
        // rows = c, cols = (b,ni); Hts[b][c+1+s(ni)][pi(ni)] = relu(acc+bs[c])
        const int gb = col0 + wn;
        const int b  = gb >> 8;
        const int gl = gb & 255;
        const int nib = gl + fr;
        u16* HtsW = auxout + (size_t)b * 514 * 256;
        const int px = gl + 4 * fr;
        const int s0 = shf(nib), s3 = shf(nib + 48);
        #pragma unroll
        for (int m = 0; m < 4; ++m) {
            #pragma unroll
            for (int j = 0; j < 4; ++j) {
                const int c = row0 + wm + m * 16 + q * 4 + j;
                const float bsv = bias[c];
                u16 vv[4];
                #pragma unroll
                for (int n = 0; n < 4; ++n)
                    vv[n] = f2b(fmaxf(acc[m][n][j] + bsv, 0.0f));
                if (s0 == s3) {
                    ushort4 v4 = {vv[0], vv[1], vv[2], vv[3]};
                    *(ushort4*)&HtsW[(size_t)(c + 1 + s0) * 256 + px] = v4;
                } else {
                    #pragma unroll
                    for (int n = 0; n < 4; ++n)
                        HtsW[(size_t)(c + 1 + shf(nib + n * 16)) * 256 + px + n] = vv[n];
                }
            }
        }
    } else if (MODE == 2) {
        #pragma unroll
        for (int m = 0; m < 4; ++m) {
            #pragma unroll
            for (int j = 0; j < 4; ++j) {
                const int row = row0 + wm + m * 16 + q * 4 + j;
                #pragma unroll
                for (int n = 0; n < 4; ++n) {
                    const int col = col0 + wn + n * 16 + fr;
                    ((float*)outv)[(size_t)row * 512 + col] =
                        acc[m][n][j] + bias[col] + res[(size_t)row * 512 + col];
                }
            }
        }
    } else {
        // conv: rows = no, cols = c; Y[b][no][pi(c)]; SEpart per (ct,wn) slot
        const int cb = col0 + wn;
        const int px = cb + 4 * fr;
        const int sslot = (col0 >> 7) * 2 + (wn >> 6);
        #pragma unroll
        for (int m = 0; m < 4; ++m) {
            #pragma unroll
            for (int j = 0; j < 4; ++j) {
                const int no = wm + m * 16 + q * 4 + j;
                const float bcv = bias[no];
                float p = 0.0f;
                u16 vv[4];
                #pragma unroll
                for (int n = 0; n < 4; ++n) {
                    float v = acc[m][n][j];
                    vv[n] = f2b(v + bcv);
                    p += v;
                }
                ushort4 v4 = {vv[0], vv[1], vv[2], vv[3]};
                *(ushort4*)&auxout[((size_t)bidx * NN + no) * CCH + px] = v4;
                p += __shfl_xor(p, 1);
                p += __shfl_xor(p, 2);
                p += __shfl_xor(p, 4);
                p += __shfl_xor(p, 8);
                if (fr == 0)
                    SEpart[sslot * 16384 + bidx * NN + no] = p;
            }
        }
    }
}

// ---------------- gemm1 phase: 8-phase 256x256xBK64, pi stores, ex from EX ----------------
static __device__ void gemm1_phase(
    const u16* __restrict__ Yb, const u16* __restrict__ Wf1t,
    const float* __restrict__ bf1, u16* __restrict__ T,
    const float* __restrict__ EX, char* ldsraw, const int bid, const int tid)
{
    u16* Ab0 = (u16*)ldsraw;                   // [2][256*64]
    u16* Bb0 = (u16*)(ldsraw + 65536);         // [2][256*64]
    float* exs = (float*)(ldsraw + 131072);    // [256]

    const int l = tid & 63;
    const int w = tid >> 6;
    const int work = (bid & 7) * 32 + (bid >> 3);
    const int row0 = (work >> 2) * 256;        // = batch * 256
    const int col0 = (work & 3) * 256;

    const u16* Aab = Yb   + (size_t)row0 * 512;
    const u16* Bab = Wf1t + (size_t)col0 * 512;

    const int wm = (w >> 2) * 128;
    const int wn = (w & 3) * 64;
    const int fr = l & 15;
    const int q  = l >> 4;
    const int r7 = fr & 7;

    if (tid < 256) exs[tid] = EX[row0 + tid];
    __syncthreads();                           // exs visible; vmcnt drained

    const int strow = tid >> 3;
    const int sslot = tid & 7;
    const int gslot = sslot ^ (strow & 7);
    const size_t goff = (size_t)strow * 512 + gslot * 8;
    const int     loff = strow * 64 + sslot * 8;

    auto stageA = [&](int c, int kt, int j) {
        gll16(Aab + (size_t)(j * 64) * 512 + kt * 64 + goff,
              &Ab0[c * 16384 + j * 64 * 64 + loff]);
    };
    auto stageB = [&](int c, int kt, int j) {
        gll16(Bab + (size_t)(j * 64) * 512 + kt * 64 + goff,
              &Bb0[c * 16384 + j * 64 * 64 + loff]);
    };

    stageA(0, 0, 0); stageA(0, 0, 1); stageA(0, 0, 2); stageA(0, 0, 3);
    stageB(0, 0, 0); stageB(0, 0, 1); stageB(0, 0, 2); stageB(0, 0, 3);
    stageA(1, 1, 0); stageA(1, 1, 2);
    stageB(1, 1, 0); stageB(1, 1, 1); stageB(1, 1, 2); stageB(1, 1, 3);

    const f32x4 zero = {0.0f, 0.0f, 0.0f, 0.0f};
    f32x4 acc[8][4];
    #pragma unroll
    for (int m = 0; m < 8; ++m)
        #pragma unroll
        for (int n = 0; n < 4; ++n) acc[m][n] = zero;

    s16x8 afv[4][2], bfv[4][2];

#define LDA8(c, r, ks) (*(const s16x8*)&Ab0[(c) * 16384 + (r) * 64 + (((((ks) << 2) + q) ^ r7) << 3)])
#define LDB8(c, r, ks) (*(const s16x8*)&Bb0[(c) * 16384 + (r) * 64 + (((((ks) << 2) + q) ^ r7) << 3)])

    for (int t = 0; t < 8; ++t) {
        const int c = t & 1;
        // P0
        if (t < 7) { stageA(c ^ 1, t + 1, 1); stageA(c ^ 1, t + 1, 3); VM8; }
        else       { VM0; }
        __builtin_amdgcn_s_barrier();
        MEMB;
        #pragma unroll
        for (int m = 0; m < 4; ++m) {
            afv[m][0] = LDA8(c, wm + m * 16 + fr, 0);
            afv[m][1] = LDA8(c, wm + m * 16 + fr, 1);
        }
        #pragma unroll
        for (int n = 0; n < 2; ++n) {
            bfv[n][0] = LDB8(c, wn + n * 16 + fr, 0);
            bfv[n][1] = LDB8(c, wn + n * 16 + fr, 1);
        }
        LGKM0;
        __builtin_amdgcn_s_setprio(1);
        #pragma unroll
        for (int m = 0; m < 4; ++m)
            #pragma unroll
            for (int n = 0; n < 2; ++n) {
                acc[m][n] = __builtin_amdgcn_mfma_f32_16x16x32_bf16(afv[m][0], bfv[n][0], acc[m][n], 0, 0, 0);
                acc[m][n] = __builtin_amdgcn_mfma_f32_16x16x32_bf16(afv[m][1], bfv[n][1], acc[m][n], 0, 0, 0);
            }
        __builtin_amdgcn_s_setprio(0);
        __builtin_amdgcn_s_barrier();
        // P1
        if (t < 6) { stageA(c, t + 2, 0); stageA(c, t + 2, 2); }
        #pragma unroll
        for (int n = 2; n < 4; ++n) {
            bfv[n][0] = LDB8(c, wn + n * 16 + fr, 0);
            bfv[n][1] = LDB8(c, wn + n * 16 + fr, 1);
        }
        LGKM0;
        __builtin_amdgcn_s_setprio(1);
        #pragma unroll
        for (int m = 0; m < 4; ++m)
            #pragma unroll
            for (int n = 2; n < 4; ++n) {
                acc[m][n] = __builtin_amdgcn_mfma_f32_16x16x32_bf16(afv[m][0], bfv[n][0], acc[m][n], 0, 0, 0);
                acc[m][n] = __builtin_amdgcn_mfma_f32_16x16x32_bf16(afv[m][1], bfv[n][1], acc[m][n], 0, 0, 0);
            }
        __builtin_amdgcn_s_setprio(0);
        __builtin_amdgcn_s_barrier();
        // P2
        if (t < 6) { stageB(c, t + 2, 0); stageB(c, t + 2, 1); }
        #pragma unroll
        for (int m = 0; m < 4; ++m) {
            afv[m][0] = LDA8(c, wm + 64 + m * 16 + fr, 0);
            afv[m][1] = LDA8(c, wm + 64 + m * 16 + fr, 1);
        }
        LGKM0;
        __builtin_amdgcn_s_setprio(1);
        #pragma unroll
        for (int m = 0; m < 4; ++m)
            #pragma unroll
            for (int n = 0; n < 2; ++n) {
                acc[4 + m][n] = __builtin_amdgcn_mfma_f32_16x16x32_bf16(afv[m][0], bfv[n][0], acc[4 + m][n], 0, 0, 0);
                acc[4 + m][n] = __builtin_amdgcn_mfma_f32_16x16x32_bf16(afv[m][1], bfv[n][1], acc[4 + m][n], 0, 0, 0);
            }
        __builtin_amdgcn_s_setprio(0);
        __builtin_amdgcn_s_barrier();
        // P3
        if (t < 6) { stageB(c, t + 2, 2); stageB(c, t + 2, 3); }
        __builtin_amdgcn_s_setprio(1);
        #pragma unroll
        for (int m = 0; m < 4; ++m)
            #pragma unroll
            for (int n = 2; n < 4; ++n) {
                acc[4 + m][n] = __builtin_amdgcn_mfma_f32_16x16x32_bf16(afv[m][0], bfv[n][0], acc[4 + m][n], 0, 0, 0);
                acc[4 + m][n] = __builtin_amdgcn_mfma_f32_16x16x32_bf16(afv[m][1], bfv[n][1], acc[4 + m][n], 0, 0, 0);
            }
        __builtin_amdgcn_s_setprio(0);
        __builtin_amdgcn_s_barrier();
    }

    const int cgb = col0 + wn;
    float bval[4];
    #pragma unroll
    for (int n = 0; n < 4; ++n) bval[n] = bf1[cgb + n * 16 + fr];
    #pragma unroll
    for (int m = 0; m < 8; ++m) {
        #pragma unroll
        for (int j = 0; j < 4; ++j) {
            const int rl  = wm + m * 16 + q * 4 + j;
            const int row = row0 + rl;
            const float sc = exs[rl];
            u16 vv[4];
            #pragma unroll
            for (int n = 0; n < 4; ++n)
                vv[n] = f2b(fmaxf(acc[m][n][j] * sc + bval[n], 0.0f));
            ushort4 v4 = {vv[0], vv[1], vv[2], vv[3]};
            *(ushort4*)&T[(size_t)row * 1024 + cgb + 4 * fr] = v4;
        }
    }
#undef LDA8
#undef LDB8
}

// ---------------- the fused persistent kernel ----------------
__global__ __launch_bounds__(512, 1) void mega_kernel(
    const float* __restrict__ x, const float* __restrict__ ln_g,
    const float* __restrict__ ln_b,
    const float* __restrict__ Ws,  const float* __restrict__ bs,
    const float* __restrict__ Wc,  const float* __restrict__ bc,
    const float* __restrict__ We1, const float* __restrict__ be1,
    const float* __restrict__ We2, const float* __restrict__ be2,
    const float* __restrict__ Wf1, const float* __restrict__ bf1,
    const float* __restrict__ Wf2, const float* __restrict__ bf2,
    float* __restrict__ out,
    u16* XN, u16* Y, u16* Hts, u16* T,
    u16* Wst, u16* Wf1t, u16* Wf2t, u16* Wc3,
    float* SEpart, float* EX, unsigned* bar)
{
    __shared__ __align__(16) char ldsraw[147456];
    const int tid = threadIdx.x;
    const int bid = blockIdx.x;

    // ---- phase 0: weight prep + Hts edge zero + LayerNorm (25 tasks/block) ----
    {
        float* t = (float*)ldsraw;
        for (int it = 0; it < 25; ++it) {
            const int ob = bid * 25 + it;
            __syncthreads();
            const int t2 = tid & 255;          // halves run duplicate (benign)
            if (ob < 256) {
                wtc_body(Ws, Wst, 512, 512, ob & 15, ob >> 4, t, false, t2);
            } else if (ob < 768) {
                int idx = ob - 256;
                wtc_body(Wf1, Wf1t, 512, 1024, idx & 31, idx >> 5, t, true, t2);
            } else if (ob < 1280) {
                int idx = ob - 768;
                wtc_body(Wf2, Wf2t, 1024, 512, idx & 15, idx >> 4, t, true, t2);
            } else if (ob < 2048) {
                int idx = (ob - 1280) * 256 + t2;
                int xloc = idx & 255;
                int o = (idx >> 8) & 255;
                int k = idx >> 16;
                int il = (xloc & ~63) | ((xloc & 63) >> 2) | ((xloc & 3) << 4);
                Wc3[idx] = f2b(Wc[((size_t)o * NN + il) * 3 + k]);
            } else if (ob < 2304) {
                int idx = (ob - 2048) * 256 + t2;
                int b   = idx >> 10;
                int rem = idx & 1023;
                int rr  = rem >> 8;
                int r   = (rr & 1) + (rr >> 1) * 512;
                Hts[((size_t)b * 514 + r) * 256 + (rem & 255)] = 0;
            } else {
                const int l = t2 & 63;
                const int r = (ob - 2304) * 4 + (t2 >> 6);
                const float4* xr = (const float4*)(x + (size_t)r * CCH);
                float4 v1 = xr[l];
                float4 v2 = xr[l + 64];
                float s  = v1.x + v1.y + v1.z + v1.w + v2.x + v2.y + v2.z + v2.w;
                float ss = v1.x*v1.x + v1.y*v1.y + v1.z*v1.z + v1.w*v1.w
                         + v2.x*v2.x + v2.y*v2.y + v2.z*v2.z + v2.w*v2.w;
                #pragma unroll
                for (int o = 32; o > 0; o >>= 1) {
                    s  += __shfl_xor(s, o);
                    ss += __shfl_xor(ss, o);
                }
                float mu  = s * (1.0f / CCH);
                float var = ss * (1.0f / CCH) - mu * mu;
                float rs  = rsqrtf(var + 1e-5f);
                float4 g1 = ((const float4*)ln_g)[l],   g2 = ((const float4*)ln_g)[l + 64];
                float4 b1 = ((const float4*)ln_b)[l],   b2 = ((const float4*)ln_b)[l + 64];
                ushort4 o1, o2;
                o1.x = f2b((v1.x - mu) * rs * g1.x + b1.x);
                o1.y = f2b((v1.y - mu) * rs * g1.y + b1.y);
                o1.z = f2b((v1.z - mu) * rs * g1.z + b1.z);
                o1.w = f2b((v1.w - mu) * rs * g1.w + b1.w);
                o2.x = f2b((v2.x - mu) * rs * g2.x + b2.x);
                o2.y = f2b((v2.y - mu) * rs * g2.y + b2.y);
                o2.z = f2b((v2.z - mu) * rs * g2.z + b2.z);
                o2.w = f2b((v2.w - mu) * rs * g2.w + b2.w);
                ushort4* orow = (ushort4*)(XN + (size_t)r * CCH);
                orow[l]      = o1;
                orow[l + 64] = o2;
            }
        }
    }
    gbar(bar, 256);

    // ---- phase 1: Hts = shifted-transpose(relu(Ws^T @ XN^T + bs)) ----
    gemm_phase<0>(Wst, XN, bs, nullptr, nullptr, Hts, nullptr, ldsraw, bid, tid);
    gbar(bar, 512);

    // ---- phase 2: Y = conv1d(shift(H)) + bc ; SEpart row-sum partials ----
    gemm_phase<3>(Wc3, Hts, bc, nullptr, nullptr, Y, SEpart, ldsraw, bid, tid);
    gbar(bar, 768);

    // ---- phase 3: EX = sigmoid(MLP(se))  (blocks 0..63) ----
    if (bid < 64) {
        float* sse = (float*)ldsraw;
        float* e1f = (float*)(ldsraw + 1024);
        if (tid < 256) {
            int o = bid * 256 + tid;
            float sum = 0.0f;
            #pragma unroll
            for (int i = 0; i < 8; ++i) sum += SEpart[i * 16384 + o];
            sse[tid] = sum * (1.0f / CCH) + bc[tid];
        }
        __syncthreads();
        if (tid < 32) {
            float a = be1[tid];
            #pragma unroll 8
            for (int i = 0; i < 256; ++i) a += sse[i] * We1[i * 32 + tid];
            e1f[tid] = fmaxf(a, 0.0f);
        }
        __syncthreads();
        if (tid < 256) {
            float a = be2[tid];
            #pragma unroll
            for (int j = 0; j < 32; ++j) a += e1f[j] * We2[j * 256 + tid];
            EX[bid * 256 + tid] = 1.0f / (1.0f + expf(-a));
        }
    }
    gbar(bar, 1024);

    // ---- phase 4: T = relu((Y*ex) @ Wf1 + bf1)  (8-phase 256x256) ----
    gemm1_phase(Y, Wf1t, bf1, T, EX, ldsraw, bid, tid);
    gbar(bar, 1280);

    // ---- phase 5: out = T @ Wf2 + bf2 + x ----
    gemm_phase<2>(T, Wf2t, bf2, x, out, nullptr, nullptr, ldsraw, bid, tid);
}

extern "C" void kernel_launch(void* const* d_in, const int* in_sizes, int n_in,
                              void* d_out, int out_size, void* d_ws, size_t ws_size,
                              hipStream_t stream) {
    const float* x    = (const float*)d_in[0];
    const float* ln_g = (const float*)d_in[1];
    const float* ln_b = (const float*)d_in[2];
    const float* Ws   = (const float*)d_in[3];
    const float* bs   = (const float*)d_in[4];
    const float* Wc   = (const float*)d_in[5];
    const float* bc   = (const float*)d_in[6];
    const float* We1  = (const float*)d_in[7];
    const float* be1  = (const float*)d_in[8];
    const float* We2  = (const float*)d_in[9];
    const float* be2  = (const float*)d_in[10];
    const float* Wf1  = (const float*)d_in[11];
    const float* bf1  = (const float*)d_in[12];
    const float* Wf2  = (const float*)d_in[13];
    const float* bf2  = (const float*)d_in[14];
    float* out = (float*)d_out;
    char* w8   = (char*)d_ws;

    // workspace (no overlays):
    //   [0,16M)            XN bf16 16384x512
    //   [16M,32M)          Y  bf16 16384x512 (pi-permuted c)
    //   [32M,~48.06M)      Hts bf16 64x514x256
    //   [48.06M,~80.06M)   T  bf16 16384x1024 (pi-permuted cols)
    //   [~80.06M ...]      tail: SEpart, Wst, Wf1t, Wf2t, Wc3, EX, bar
    u16* XN  = (u16*)(w8);
    u16* Y   = (u16*)(w8 + 16777216);
    u16* Hts = (u16*)(w8 + 33554432);
    u16* T   = (u16*)(w8 + 50397184);
    char* tail = w8 + 83951616;
    float* SEpart = (float*)(tail);                 // 512K [8][64][256]
    u16* Wst      = (u16*)(tail + 524288);          // 512K
    u16* Wf1t     = (u16*)(tail + 1048576);         // 1M
    u16* Wf2t     = (u16*)(tail + 2097152);         // 1M
    u16* Wc3      = (u16*)(tail + 3145728);         // 384K
    float* EX     = (float*)(tail + 3538944);       // 64K
    unsigned* bar = (unsigned*)(tail + 3604480);    // barrier counter

    hipMemsetAsync(bar, 0, 64, stream);
    mega_kernel<<<256, 512, 0, stream>>>(
        x, ln_g, ln_b, Ws, bs, Wc, bc, We1, be1, We2, be2,
        Wf1, bf1, Wf2, bf2, out,
        XN, Y, Hts, T, Wst, Wf1t, Wf2t, Wc3, SEpart, EX, bar);
}

// Round 11
// 218.657 us; speedup vs baseline: 1.3414x; 1.3414x over previous
//
#include <hip/hip_runtime.h>
#include <hip/hip_bf16.h>
#include <math.h>

#define BB 64
#define NN 256
#define CCH 512

typedef unsigned short u16;
typedef __attribute__((ext_vector_type(8))) short s16x8;
typedef __attribute__((ext_vector_type(4))) float f32x4;

#define AS1 __attribute__((address_space(1)))
#define AS3 __attribute__((address_space(3)))

static __device__ __forceinline__ u16 f2b(float f) {
    __hip_bfloat16 h = __float2bfloat16(f);
    union { __hip_bfloat16 h; u16 u; } x; x.h = h; return x.u;
}
static __device__ __forceinline__ void gll16(const void* g, void* l) {
    __builtin_amdgcn_global_load_lds((const AS1 unsigned int*)g,
                                     (AS3 unsigned int*)l, 16, 0, 0);
}
static __device__ __forceinline__ int shf(int ni) {
    return (ni < 86) ? -1 : (ni < 172 ? 0 : 1);
}

#define VM8  asm volatile("s_waitcnt vmcnt(8)" ::: "memory")
#define VM6  asm volatile("s_waitcnt vmcnt(6)" ::: "memory")
#define VM0  asm volatile("s_waitcnt vmcnt(0)" ::: "memory")
#define LGKM0 asm volatile("s_waitcnt lgkmcnt(0)" ::: "memory")
#define MEMB asm volatile("" ::: "memory")

// ---- device-scope grid barrier: RELAXED spin, acquire ONCE after exit ----
// (r10 bug: ACQUIRE-ordered spin loads emit buffer_inv sc1 every poll ->
//  continuous L2 invalidation chip-wide. Relaxed polls are plain loads.)
static __device__ __forceinline__ void gbar(unsigned* bar, unsigned target)
{
    __syncthreads();                       // drains each wave's vmem/lds
    if (threadIdx.x == 0) {
        __threadfence();                   // release: local L2 writeback
        __hip_atomic_fetch_add(bar, 1u, __ATOMIC_RELAXED, __HIP_MEMORY_SCOPE_AGENT);
        unsigned spins = 0;
        while (__hip_atomic_load(bar, __ATOMIC_RELAXED, __HIP_MEMORY_SCOPE_AGENT) < target) {
            __builtin_amdgcn_s_sleep(8);
            if (++spins > 16000000u) break; // escape valve: fail visibly, never hang
        }
        __threadfence();                   // acquire once: invalidate stale lines
    }
    __syncthreads();
}

// ---------------- phase 0 helpers ----------------
// k-permutation: stored location = (k & ~63) | ((k&15)<<2) | ((k>>4)&3)
static __device__ __forceinline__ void wtc_body(const float* __restrict__ W,
    u16* __restrict__ Wt, int K, int N, int bx, int by, float* t, bool perm, int t2)
{
    int n0 = bx * 32, k0 = by * 32;
    int tx = t2 & 31, ty = t2 >> 5;
    #pragma unroll
    for (int i = 0; i < 4; ++i)
        t[(ty + i * 8) * 33 + tx] = W[(size_t)(k0 + ty + i * 8) * N + n0 + tx];
    __syncthreads();
    int kl = k0 + tx;
    int kp = perm ? ((kl & ~63) | ((kl & 15) << 2) | ((kl >> 4) & 3)) : kl;
    #pragma unroll
    for (int i = 0; i < 4; ++i)
        Wt[(size_t)(n0 + ty + i * 8) * K + kp] = f2b(t[tx * 33 + ty + i * 8]);
}

// ---------------- 6-slot pipelined GEMM phase (modes 0, 2, 3; BN=128) ----------------
// 64x64 wave tiles (4Mx2N), pi-permuted ushort4 epilogue stores.
template<int MODE>
static __device__ void gemm_phase(
    const u16* __restrict__ A, const u16* __restrict__ Bt,
    const float* __restrict__ bias, const float* __restrict__ res,
    void* __restrict__ outv, u16* __restrict__ auxout,
    float* __restrict__ SEpart, char* ldsraw, const int bid, const int tid)
{
    constexpr int NK = (MODE == 2) ? 32 : (MODE == 3) ? 24 : 16;
    constexpr int SA = (MODE == 2) ? 1024 : 512;
    constexpr int SB = (MODE == 2) ? 1024 : 512;

    u16* Asm = (u16*)ldsraw;              // 6*8192 u16 = 96KB
    u16* Bsm = (u16*)(ldsraw + 98304);    // 6*4096 u16 = 48KB

    const int l = tid & 63;
    const int w = tid >> 6;
    const int work = (bid & 7) * 32 + (bid >> 3);

    int row0, col0, bidx = 0;
    if (MODE == 0)      { row0 = (work >> 7) * 256; col0 = (work & 127) * 128; }
    else if (MODE == 2) { row0 = (work >> 2) * 256; col0 = (work & 3) * 128; }
    else                { row0 = 0; bidx = work >> 2; col0 = (work & 3) * 128; }

    const u16* Aab  = A + (size_t)row0 * SA;
    const u16* Bab  = Bt + (size_t)col0 * SB;
    const u16* HtsB = Bt + (size_t)bidx * 514 * 256;

    const int wm = (w >> 1) * 64;
    const int wn = (w & 1) * 64;
    const int fr = l & 15;
    const int q  = l >> 4;
    const int kofs = ((q ^ ((l >> 1) & 3)) * 8);

    const f32x4 zero = {0.0f, 0.0f, 0.0f, 0.0f};
    f32x4 acc[4][4];
    #pragma unroll
    for (int m = 0; m < 4; ++m)
        #pragma unroll
        for (int n = 0; n < 4; ++n) acc[m][n] = zero;

    const int kc0 = ((tid & 3) ^ ((tid >> 3) & 3)) * 8;
    const int srow = tid >> 2;

    auto stage = [&](int u, int slot) {
        u16* ald = Asm + slot * 8192 + w * 512;
        u16* bld = Bsm + slot * 4096 + w * 512;
        if (MODE == 3) {
            const int kseg = u >> 3, kb = (u & 7) * 32 + kc0;
            gll16(A + kseg * 65536 + srow * 256 + kb, ald);
            gll16(A + kseg * 65536 + (srow + 128) * 256 + kb, ald + 4096);
            gll16(HtsB + (size_t)(col0 + srow + kseg) * 256 + kb, bld);
        } else {
            const int kb = u * 32 + kc0;
            gll16(Aab + (size_t)srow * SA + kb, ald);
            gll16(Aab + (size_t)(srow + 128) * SA + kb, ald + 4096);
            gll16(Bab + (size_t)srow * SB + kb, bld);
        }
    };

    stage(0, 0); stage(1, 1); stage(2, 2); stage(3, 3);
    int sa = 0;
    constexpr int NV = NK / 2;
    for (int v = 0; v < NV; ++v) {
        if (v + 1 < NV) { VM6; } else { VM0; }
        __builtin_amdgcn_s_barrier();
        MEMB;
        const int sb = sa + 1;
        s16x8 b0[4], af0[4];
        #pragma unroll
        for (int n = 0; n < 4; ++n)
            b0[n] = *(const s16x8*)&Bsm[sa * 4096 + (wn + n * 16 + fr) * 32 + kofs];
        #pragma unroll
        for (int m = 0; m < 4; ++m)
            af0[m] = *(const s16x8*)&Asm[sa * 8192 + (wm + m * 16 + fr) * 32 + kofs];
        const int u2 = 2 * v + 4;
        if (u2 < NK) {
            int st = sa + 4; if (st >= 6) st -= 6;
            stage(u2, st);
            int st1 = st + 1; if (st1 >= 6) st1 -= 6;
            stage(u2 + 1, st1);
        }
        __builtin_amdgcn_s_setprio(1);
        #pragma unroll
        for (int m = 0; m < 4; ++m)
            #pragma unroll
            for (int n = 0; n < 4; ++n)
                acc[m][n] = __builtin_amdgcn_mfma_f32_16x16x32_bf16(af0[m], b0[n], acc[m][n], 0, 0, 0);
        __builtin_amdgcn_s_setprio(0);
        s16x8 b1[4], af1[4];
        #pragma unroll
        for (int n = 0; n < 4; ++n)
            b1[n] = *(const s16x8*)&Bsm[sb * 4096 + (wn + n * 16 + fr) * 32 + kofs];
        #pragma unroll
        for (int m = 0; m < 4; ++m)
            af1[m] = *(const s16x8*)&Asm[sb * 8192 + (wm + m * 16 + fr) * 32 + kofs];
        __builtin_amdgcn_s_setprio(1);
        #pragma unroll
        for (int m = 0; m < 4; ++m)
            #pragma unroll
            for (int n = 0; n < 4; ++n)
                acc[m][n] = __builtin_amdgcn_mfma_f32_16x16x32_bf16(af1[m], b1[n], acc[m][n], 0, 0, 0);
        __builtin_amdgcn_s_setprio(0);
        MEMB;
        sa += 2; if (sa >= 6) sa = 0;
    }

    if (MODE == 0) {
        // rows = c, cols = (b,ni); Hts[b][c+1+s(ni)][pi(ni)] = relu(acc+bs[c])
        const int gb = col0 + wn;
        const int b  = gb >> 8;
        const int gl = gb & 255;
        const int nib = gl + fr;
        u16* HtsW = auxout + (size_t)b * 514 * 256;
        const int px = gl + 4 * fr;
        const int s0 = shf(nib), s3 = shf(nib + 48);
        #pragma unroll
        for (int m = 0; m < 4; ++m) {
            #pragma unroll
            for (int j = 0; j < 4; ++j) {
                const int c = row0 + wm + m * 16 + q * 4 + j;
                const float bsv = bias[c];
                u16 vv[4];
                #pragma unroll
                for (int n = 0; n < 4; ++n)
                    vv[n] = f2b(fmaxf(acc[m][n][j] + bsv, 0.0f));
                if (s0 == s3) {
                    ushort4 v4 = {vv[0], vv[1], vv[2], vv[3]};
                    *(ushort4*)&HtsW[(size_t)(c + 1 + s0) * 256 + px] = v4;
                } else {
                    #pragma unroll
                    for (int n = 0; n < 4; ++n)
                        HtsW[(size_t)(c + 1 + shf(nib + n * 16)) * 256 + px + n] = vv[n];
                }
            }
        }
    } else if (MODE == 2) {
        #pragma unroll
        for (int m = 0; m < 4; ++m) {
            #pragma unroll
            for (int j = 0; j < 4; ++j) {
                const int row = row0 + wm + m * 16 + q * 4 + j;
                #pragma unroll
                for (int n = 0; n < 4; ++n) {
                    const int col = col0 + wn + n * 16 + fr;
                    ((float*)outv)[(size_t)row * 512 + col] =
                        acc[m][n][j] + bias[col] + res[(size_t)row * 512 + col];
                }
            }
        }
    } else {
        // conv: rows = no, cols = c; Y[b][no][pi(c)]; SEpart per (ct,wn) slot
        const int cb = col0 + wn;
        const int px = cb + 4 * fr;
        const int sslot = (col0 >> 7) * 2 + (wn >> 6);
        #pragma unroll
        for (int m = 0; m < 4; ++m) {
            #pragma unroll
            for (int j = 0; j < 4; ++j) {
                const int no = wm + m * 16 + q * 4 + j;
                const float bcv = bias[no];
                float p = 0.0f;
                u16 vv[4];
                #pragma unroll
                for (int n = 0; n < 4; ++n) {
                    float v = acc[m][n][j];
                    vv[n] = f2b(v + bcv);
                    p += v;
                }
                ushort4 v4 = {vv[0], vv[1], vv[2], vv[3]};
                *(ushort4*)&auxout[((size_t)bidx * NN + no) * CCH + px] = v4;
                p += __shfl_xor(p, 1);
                p += __shfl_xor(p, 2);
                p += __shfl_xor(p, 4);
                p += __shfl_xor(p, 8);
                if (fr == 0)
                    SEpart[sslot * 16384 + bidx * NN + no] = p;
            }
        }
    }
}

// ---------------- gemm1 phase: 8-phase 256x256xBK64, pi stores, ex from EX ----------------
static __device__ void gemm1_phase(
    const u16* __restrict__ Yb, const u16* __restrict__ Wf1t,
    const float* __restrict__ bf1, u16* __restrict__ T,
    const float* __restrict__ EX, char* ldsraw, const int bid, const int tid)
{
    u16* Ab0 = (u16*)ldsraw;                   // [2][256*64]
    u16* Bb0 = (u16*)(ldsraw + 65536);         // [2][256*64]
    float* exs = (float*)(ldsraw + 131072);    // [256]

    const int l = tid & 63;
    const int w = tid >> 6;
    const int work = (bid & 7) * 32 + (bid >> 3);
    const int row0 = (work >> 2) * 256;        // = batch * 256
    const int col0 = (work & 3) * 256;

    const u16* Aab = Yb   + (size_t)row0 * 512;
    const u16* Bab = Wf1t + (size_t)col0 * 512;

    const int wm = (w >> 2) * 128;
    const int wn = (w & 3) * 64;
    const int fr = l & 15;
    const int q  = l >> 4;
    const int r7 = fr & 7;

    if (tid < 256) exs[tid] = EX[row0 + tid];
    __syncthreads();                           // exs visible; vmcnt drained

    const int strow = tid >> 3;
    const int sslot = tid & 7;
    const int gslot = sslot ^ (strow & 7);
    const size_t goff = (size_t)strow * 512 + gslot * 8;
    const int     loff = strow * 64 + sslot * 8;

    auto stageA = [&](int c, int kt, int j) {
        gll16(Aab + (size_t)(j * 64) * 512 + kt * 64 + goff,
              &Ab0[c * 16384 + j * 64 * 64 + loff]);
    };
    auto stageB = [&](int c, int kt, int j) {
        gll16(Bab + (size_t)(j * 64) * 512 + kt * 64 + goff,
              &Bb0[c * 16384 + j * 64 * 64 + loff]);
    };

    stageA(0, 0, 0); stageA(0, 0, 1); stageA(0, 0, 2); stageA(0, 0, 3);
    stageB(0, 0, 0); stageB(0, 0, 1); stageB(0, 0, 2); stageB(0, 0, 3);
    stageA(1, 1, 0); stageA(1, 1, 2);
    stageB(1, 1, 0); stageB(1, 1, 1); stageB(1, 1, 2); stageB(1, 1, 3);

    const f32x4 zero = {0.0f, 0.0f, 0.0f, 0.0f};
    f32x4 acc[8][4];
    #pragma unroll
    for (int m = 0; m < 8; ++m)
        #pragma unroll
        for (int n = 0; n < 4; ++n) acc[m][n] = zero;

    s16x8 afv[4][2], bfv[4][2];

#define LDA8(c, r, ks) (*(const s16x8*)&Ab0[(c) * 16384 + (r) * 64 + (((((ks) << 2) + q) ^ r7) << 3)])
#define LDB8(c, r, ks) (*(const s16x8*)&Bb0[(c) * 16384 + (r) * 64 + (((((ks) << 2) + q) ^ r7) << 3)])

    for (int t = 0; t < 8; ++t) {
        const int c = t & 1;
        // P0
        if (t < 7) { stageA(c ^ 1, t + 1, 1); stageA(c ^ 1, t + 1, 3); VM8; }
        else       { VM0; }
        __builtin_amdgcn_s_barrier();
        MEMB;
        #pragma unroll
        for (int m = 0; m < 4; ++m) {
            afv[m][0] = LDA8(c, wm + m * 16 + fr, 0);
            afv[m][1] = LDA8(c, wm + m * 16 + fr, 1);
        }
        #pragma unroll
        for (int n = 0; n < 2; ++n) {
            bfv[n][0] = LDB8(c, wn + n * 16 + fr, 0);
            bfv[n][1] = LDB8(c, wn + n * 16 + fr, 1);
        }
        LGKM0;
        __builtin_amdgcn_s_setprio(1);
        #pragma unroll
        for (int m = 0; m < 4; ++m)
            #pragma unroll
            for (int n = 0; n < 2; ++n) {
                acc[m][n] = __builtin_amdgcn_mfma_f32_16x16x32_bf16(afv[m][0], bfv[n][0], acc[m][n], 0, 0, 0);
                acc[m][n] = __builtin_amdgcn_mfma_f32_16x16x32_bf16(afv[m][1], bfv[n][1], acc[m][n], 0, 0, 0);
            }
        __builtin_amdgcn_s_setprio(0);
        __builtin_amdgcn_s_barrier();
        // P1
        if (t < 6) { stageA(c, t + 2, 0); stageA(c, t + 2, 2); }
        #pragma unroll
        for (int n = 2; n < 4; ++n) {
            bfv[n][0] = LDB8(c, wn + n * 16 + fr, 0);
            bfv[n][1] = LDB8(c, wn + n * 16 + fr, 1);
        }
        LGKM0;
        __builtin_amdgcn_s_setprio(1);
        #pragma unroll
        for (int m = 0; m < 4; ++m)
            #pragma unroll
            for (int n = 2; n < 4; ++n) {
                acc[m][n] = __builtin_amdgcn_mfma_f32_16x16x32_bf16(afv[m][0], bfv[n][0], acc[m][n], 0, 0, 0);
                acc[m][n] = __builtin_amdgcn_mfma_f32_16x16x32_bf16(afv[m][1], bfv[n][1], acc[m][n], 0, 0, 0);
            }
        __builtin_amdgcn_s_setprio(0);
        __builtin_amdgcn_s_barrier();
        // P2
        if (t < 6) { stageB(c, t + 2, 0); stageB(c, t + 2, 1); }
        #pragma unroll
        for (int m = 0; m < 4; ++m) {
            afv[m][0] = LDA8(c, wm + 64 + m * 16 + fr, 0);
            afv[m][1] = LDA8(c, wm + 64 + m * 16 + fr, 1);
        }
        LGKM0;
        __builtin_amdgcn_s_setprio(1);
        #pragma unroll
        for (int m = 0; m < 4; ++m)
            #pragma unroll
            for (int n = 0; n < 2; ++n) {
                acc[4 + m][n] = __builtin_amdgcn_mfma_f32_16x16x32_bf16(afv[m][0], bfv[n][0], acc[4 + m][n], 0, 0, 0);
                acc[4 + m][n] = __builtin_amdgcn_mfma_f32_16x16x32_bf16(afv[m][1], bfv[n][1], acc[4 + m][n], 0, 0, 0);
            }
        __builtin_amdgcn_s_setprio(0);
        __builtin_amdgcn_s_barrier();
        // P3
        if (t < 6) { stageB(c, t + 2, 2); stageB(c, t + 2, 3); }
        __builtin_amdgcn_s_setprio(1);
        #pragma unroll
        for (int m = 0; m < 4; ++m)
            #pragma unroll
            for (int n = 2; n < 4; ++n) {
                acc[4 + m][n] = __builtin_amdgcn_mfma_f32_16x16x32_bf16(afv[m][0], bfv[n][0], acc[4 + m][n], 0, 0, 0);
                acc[4 + m][n] = __builtin_amdgcn_mfma_f32_16x16x32_bf16(afv[m][1], bfv[n][1], acc[4 + m][n], 0, 0, 0);
            }
        __builtin_amdgcn_s_setprio(0);
        __builtin_amdgcn_s_barrier();
    }

    const int cgb = col0 + wn;
    float bval[4];
    #pragma unroll
    for (int n = 0; n < 4; ++n) bval[n] = bf1[cgb + n * 16 + fr];
    #pragma unroll
    for (int m = 0; m < 8; ++m) {
        #pragma unroll
        for (int j = 0; j < 4; ++j) {
            const int rl  = wm + m * 16 + q * 4 + j;
            const int row = row0 + rl;
            const float sc = exs[rl];
            u16 vv[4];
            #pragma unroll
            for (int n = 0; n < 4; ++n)
                vv[n] = f2b(fmaxf(acc[m][n][j] * sc + bval[n], 0.0f));
            ushort4 v4 = {vv[0], vv[1], vv[2], vv[3]};
            *(ushort4*)&T[(size_t)row * 1024 + cgb + 4 * fr] = v4;
        }
    }
#undef LDA8
#undef LDB8
}

// ---------------- the fused persistent kernel ----------------
__global__ __launch_bounds__(512, 1) void mega_kernel(
    const float* __restrict__ x, const float* __restrict__ ln_g,
    const float* __restrict__ ln_b,
    const float* __restrict__ Ws,  const float* __restrict__ bs,
    const float* __restrict__ Wc,  const float* __restrict__ bc,
    const float* __restrict__ We1, const float* __restrict__ be1,
    const float* __restrict__ We2, const float* __restrict__ be2,
    const float* __restrict__ Wf1, const float* __restrict__ bf1,
    const float* __restrict__ Wf2, const float* __restrict__ bf2,
    float* __restrict__ out,
    u16* XN, u16* Y, u16* Hts, u16* T,
    u16* Wst, u16* Wf1t, u16* Wf2t, u16* Wc3,
    float* SEpart, float* EX, unsigned* bar)
{
    __shared__ __align__(16) char ldsraw[147456];
    const int tid = threadIdx.x;
    const int bid = blockIdx.x;

    // ---- phase 0: weight prep + Hts edge zero + LayerNorm (17 units/block) ----
    {
        float* t = (float*)ldsraw;
        for (int it = 0; it < 17; ++it) {
            const int ob = bid * 17 + it;
            __syncthreads();
            const int t2 = tid & 255;          // weight tasks: halves duplicate (benign)
            if (ob < 256) {
                wtc_body(Ws, Wst, 512, 512, ob & 15, ob >> 4, t, false, t2);
            } else if (ob < 768) {
                int idx = ob - 256;
                wtc_body(Wf1, Wf1t, 512, 1024, idx & 31, idx >> 5, t, true, t2);
            } else if (ob < 1280) {
                int idx = ob - 768;
                wtc_body(Wf2, Wf2t, 1024, 512, idx & 15, idx >> 4, t, true, t2);
            } else if (ob < 2048) {
                int idx = (ob - 1280) * 256 + t2;
                int xloc = idx & 255;
                int o = (idx >> 8) & 255;
                int k = idx >> 16;
                int il = (xloc & ~63) | ((xloc & 63) >> 2) | ((xloc & 3) << 4);
                Wc3[idx] = f2b(Wc[((size_t)o * NN + il) * 3 + k]);
            } else if (ob < 2304) {
                int idx = (ob - 2048) * 256 + t2;
                int b   = idx >> 10;
                int rem = idx & 1023;
                int rr  = rem >> 8;
                int r   = (rr & 1) + (rr >> 1) * 512;
                Hts[((size_t)b * 514 + r) * 256 + (rem & 255)] = 0;
            } else {                           // LN: 8 rows/unit, all 512 threads
                const int l = tid & 63;
                const int r = (ob - 2304) * 8 + (tid >> 6);
                const float4* xr = (const float4*)(x + (size_t)r * CCH);
                float4 v1 = xr[l];
                float4 v2 = xr[l + 64];
                float s  = v1.x + v1.y + v1.z + v1.w + v2.x + v2.y + v2.z + v2.w;
                float ss = v1.x*v1.x + v1.y*v1.y + v1.z*v1.z + v1.w*v1.w
                         + v2.x*v2.x + v2.y*v2.y + v2.z*v2.z + v2.w*v2.w;
                #pragma unroll
                for (int o = 32; o > 0; o >>= 1) {
                    s  += __shfl_xor(s, o);
                    ss += __shfl_xor(ss, o);
                }
                float mu  = s * (1.0f / CCH);
                float var = ss * (1.0f / CCH) - mu * mu;
                float rs  = rsqrtf(var + 1e-5f);
                float4 g1 = ((const float4*)ln_g)[l],   g2 = ((const float4*)ln_g)[l + 64];
                float4 b1 = ((const float4*)ln_b)[l],   b2 = ((const float4*)ln_b)[l + 64];
                ushort4 o1, o2;
                o1.x = f2b((v1.x - mu) * rs * g1.x + b1.x);
                o1.y = f2b((v1.y - mu) * rs * g1.y + b1.y);
                o1.z = f2b((v1.z - mu) * rs * g1.z + b1.z);
                o1.w = f2b((v1.w - mu) * rs * g1.w + b1.w);
                o2.x = f2b((v2.x - mu) * rs * g2.x + b2.x);
                o2.y = f2b((v2.y - mu) * rs * g2.y + b2.y);
                o2.z = f2b((v2.z - mu) * rs * g2.z + b2.z);
                o2.w = f2b((v2.w - mu) * rs * g2.w + b2.w);
                ushort4* orow = (ushort4*)(XN + (size_t)r * CCH);
                orow[l]      = o1;
                orow[l + 64] = o2;
            }
        }
    }
    gbar(bar, 256);

    // ---- phase 1: Hts = shifted-transpose(relu(Ws^T @ XN^T + bs)) ----
    gemm_phase<0>(Wst, XN, bs, nullptr, nullptr, Hts, nullptr, ldsraw, bid, tid);
    gbar(bar, 512);

    // ---- phase 2: Y = conv1d(shift(H)) + bc ; SEpart row-sum partials ----
    gemm_phase<3>(Wc3, Hts, bc, nullptr, nullptr, Y, SEpart, ldsraw, bid, tid);
    gbar(bar, 768);

    // ---- phase 3: EX = sigmoid(MLP(se))  (blocks 0..63) ----
    if (bid < 64) {
        float* sse = (float*)ldsraw;
        float* e1f = (float*)(ldsraw + 1024);
        if (tid < 256) {
            int o = bid * 256 + tid;
            float sum = 0.0f;
            #pragma unroll
            for (int i = 0; i < 8; ++i) sum += SEpart[i * 16384 + o];
            sse[tid] = sum * (1.0f / CCH) + bc[tid];
        }
        __syncthreads();
        if (tid < 32) {
            float a = be1[tid];
            #pragma unroll 8
            for (int i = 0; i < 256; ++i) a += sse[i] * We1[i * 32 + tid];
            e1f[tid] = fmaxf(a, 0.0f);
        }
        __syncthreads();
        if (tid < 256) {
            float a = be2[tid];
            #pragma unroll
            for (int j = 0; j < 32; ++j) a += e1f[j] * We2[j * 256 + tid];
            EX[bid * 256 + tid] = 1.0f / (1.0f + expf(-a));
        }
    }
    gbar(bar, 1024);

    // ---- phase 4: T = relu((Y*ex) @ Wf1 + bf1)  (8-phase 256x256) ----
    gemm1_phase(Y, Wf1t, bf1, T, EX, ldsraw, bid, tid);
    gbar(bar, 1280);

    // ---- phase 5: out = T @ Wf2 + bf2 + x ----
    gemm_phase<2>(T, Wf2t, bf2, x, out, nullptr, nullptr, ldsraw, bid, tid);
}

extern "C" void kernel_launch(void* const* d_in, const int* in_sizes, int n_in,
                              void* d_out, int out_size, void* d_ws, size_t ws_size,
                              hipStream_t stream) {
    const float* x    = (const float*)d_in[0];
    const float* ln_g = (const float*)d_in[1];
    const float* ln_b = (const float*)d_in[2];
    const float* Ws   = (const float*)d_in[3];
    const float* bs   = (const float*)d_in[4];
    const float* Wc   = (const float*)d_in[5];
    const float* bc   = (const float*)d_in[6];
    const float* We1  = (const float*)d_in[7];
    const float* be1  = (const float*)d_in[8];
    const float* We2  = (const float*)d_in[9];
    const float* be2  = (const float*)d_in[10];
    const float* Wf1  = (const float*)d_in[11];
    const float* bf1  = (const float*)d_in[12];
    const float* Wf2  = (const float*)d_in[13];
    const float* bf2  = (const float*)d_in[14];
    float* out = (float*)d_out;
    char* w8   = (char*)d_ws;

    // workspace (no overlays):
    //   [0,16M)            XN bf16 16384x512
    //   [16M,32M)          Y  bf16 16384x512 (pi-permuted c)
    //   [32M,~48.06M)      Hts bf16 64x514x256
    //   [48.06M,~80.06M)   T  bf16 16384x1024 (pi-permuted cols)
    //   [~80.06M ...]      tail: SEpart, Wst, Wf1t, Wf2t, Wc3, EX, bar
    u16* XN  = (u16*)(w8);
    u16* Y   = (u16*)(w8 + 16777216);
    u16* Hts = (u16*)(w8 + 33554432);
    u16* T   = (u16*)(w8 + 50397184);
    char* tail = w8 + 83951616;
    float* SEpart = (float*)(tail);                 // 512K [8][64][256]
    u16* Wst      = (u16*)(tail + 524288);          // 512K
    u16* Wf1t     = (u16*)(tail + 1048576);         // 1M
    u16* Wf2t     = (u16*)(tail + 2097152);         // 1M
    u16* Wc3      = (u16*)(tail + 3145728);         // 384K
    float* EX     = (float*)(tail + 3538944);       // 64K
    unsigned* bar = (unsigned*)(tail + 3604480);    // barrier counter

    hipMemsetAsync(bar, 0, 64, stream);
    mega_kernel<<<256, 512, 0, stream>>>(
        x, ln_g, ln_b, Ws, bs, Wc, bc, We1, be1, We2, be2,
        Wf1, bf1, Wf2, bf2, out,
        XN, Y, Hts, T, Wst, Wf1t, Wf2t, Wc3, SEpart, EX, bar);
}

// Round 12
// 117.522 us; speedup vs baseline: 2.4957x; 1.8606x over previous
//
#include <hip/hip_runtime.h>
#include <hip/hip_bf16.h>
#include <math.h>

#define BB 64
#define NN 256
#define CCH 512

typedef unsigned short u16;
typedef __attribute__((ext_vector_type(8))) short s16x8;
typedef __attribute__((ext_vector_type(4))) float f32x4;

#define AS1 __attribute__((address_space(1)))
#define AS3 __attribute__((address_space(3)))

static __device__ __forceinline__ u16 f2b(float f) {
    __hip_bfloat16 h = __float2bfloat16(f);
    union { __hip_bfloat16 h; u16 u; } x; x.h = h; return x.u;
}
static __device__ __forceinline__ void gll16(const void* g, void* l) {
    __builtin_amdgcn_global_load_lds((const AS1 unsigned int*)g,
                                     (AS3 unsigned int*)l, 16, 0, 0);
}
static __device__ __forceinline__ int shf(int ni) {
    return (ni < 86) ? -1 : (ni < 172 ? 0 : 1);
}

#define VM8  asm volatile("s_waitcnt vmcnt(8)" ::: "memory")
#define VM4  asm volatile("s_waitcnt vmcnt(4)" ::: "memory")
#define VM0  asm volatile("s_waitcnt vmcnt(0)" ::: "memory")
#define MEMB asm volatile("" ::: "memory")

// ---------------- merged prep (weights, Hts edges) + LayerNorm ----------------
// k-permutation: stored location = (k & ~63) | ((k&15)<<2) | ((k>>4)&3)
static __device__ __forceinline__ void wtc_body(const float* __restrict__ W,
    u16* __restrict__ Wt, int K, int N, int bx, int by, float* t, bool perm)
{
    int n0 = bx * 32, k0 = by * 32;
    int tx = threadIdx.x & 31, ty = threadIdx.x >> 5;
    #pragma unroll
    for (int i = 0; i < 4; ++i)
        t[(ty + i * 8) * 33 + tx] = W[(size_t)(k0 + ty + i * 8) * N + n0 + tx];
    __syncthreads();
    int kl = k0 + tx;
    int kp = perm ? ((kl & ~63) | ((kl & 15) << 2) | ((kl >> 4) & 3)) : kl;
    #pragma unroll
    for (int i = 0; i < 4; ++i)
        Wt[(size_t)(n0 + ty + i * 8) * K + kp] = f2b(t[tx * 33 + ty + i * 8]);
}

__global__ __launch_bounds__(256) void prep_ln_kernel(
    const float* __restrict__ Ws,  u16* __restrict__ Wst,
    const float* __restrict__ Wf1, u16* __restrict__ Wf1t,
    const float* __restrict__ Wf2, u16* __restrict__ Wf2t,
    const float* __restrict__ Wc,  u16* __restrict__ Wc3,
    u16* __restrict__ Hts,
    const float* __restrict__ x, const float* __restrict__ g,
    const float* __restrict__ bta, u16* __restrict__ xnorm)
{
    __shared__ float t[32 * 33];
    int bid = blockIdx.x;
    if (bid < 256) {                       // Ws -> Wst (no perm)
        wtc_body(Ws, Wst, 512, 512, bid & 15, bid >> 4, t, false);
    } else if (bid < 768) {                // Wf1 -> Wf1t [1024][512-perm]
        int idx = bid - 256;
        wtc_body(Wf1, Wf1t, 512, 1024, idx & 31, idx >> 5, t, true);
    } else if (bid < 1280) {               // Wf2 -> Wf2t [512][1024-perm]
        int idx = bid - 768;
        wtc_body(Wf2, Wf2t, 1024, 512, idx & 15, idx >> 4, t, true);
    } else if (bid < 2048) {               // Wc3[k][o][ni-perm]
        int idx = (bid - 1280) * 256 + threadIdx.x;
        int xloc = idx & 255;
        int o = (idx >> 8) & 255;
        int k = idx >> 16;
        int il = (xloc & ~63) | ((xloc & 63) >> 2) | ((xloc & 3) << 4);
        Wc3[idx] = f2b(Wc[((size_t)o * NN + il) * 3 + k]);
    } else if (bid < 2304) {               // zero Hts edge rows {0,1,512,513}
        int idx = (bid - 2048) * 256 + threadIdx.x;
        int b   = idx >> 10;
        int rem = idx & 1023;
        int rr  = rem >> 8;
        int r   = (rr & 1) + (rr >> 1) * 512;
        Hts[((size_t)b * 514 + r) * 256 + (rem & 255)] = 0;
    } else {                               // LayerNorm, one wave per row
        const int l = threadIdx.x & 63;
        const int r = (bid - 2304) * 4 + (threadIdx.x >> 6);
        const float4* xr = (const float4*)(x + (size_t)r * CCH);
        float4 v1 = xr[l];
        float4 v2 = xr[l + 64];
        float s  = v1.x + v1.y + v1.z + v1.w + v2.x + v2.y + v2.z + v2.w;
        float ss = v1.x*v1.x + v1.y*v1.y + v1.z*v1.z + v1.w*v1.w
                 + v2.x*v2.x + v2.y*v2.y + v2.z*v2.z + v2.w*v2.w;
        #pragma unroll
        for (int o = 32; o > 0; o >>= 1) {
            s  += __shfl_xor(s, o);
            ss += __shfl_xor(ss, o);
        }
        float mu  = s * (1.0f / CCH);
        float var = ss * (1.0f / CCH) - mu * mu;
        float rs  = rsqrtf(var + 1e-5f);
        float4 g1 = ((const float4*)g)[l],   g2 = ((const float4*)g)[l + 64];
        float4 b1 = ((const float4*)bta)[l], b2 = ((const float4*)bta)[l + 64];
        ushort4 o1, o2;
        o1.x = f2b((v1.x - mu) * rs * g1.x + b1.x);
        o1.y = f2b((v1.y - mu) * rs * g1.y + b1.y);
        o1.z = f2b((v1.z - mu) * rs * g1.z + b1.z);
        o1.w = f2b((v1.w - mu) * rs * g1.w + b1.w);
        o2.x = f2b((v2.x - mu) * rs * g2.x + b2.x);
        o2.y = f2b((v2.y - mu) * rs * g2.y + b2.y);
        o2.z = f2b((v2.z - mu) * rs * g2.z + b2.z);
        o2.w = f2b((v2.w - mu) * rs * g2.w + b2.w);
        ushort4* orow = (ushort4*)(xnorm + (size_t)r * CCH);
        orow[l]      = o1;
        orow[l + 64] = o2;
    }
}

// ---------------- unified GEMM core: 128x128, 4 waves, 2 blocks/CU ----------------
// 64x64 wave tiles (2Mx2N), 4-slot LDS ring (64KB), counted vmcnt(8/4/0),
// T2 pre-swizzled k-chunks, pi-permuted ushort4 epilogue stores.
// MODE 0: A=Wst[c][k], B=XN -> Hts shifted-transpose, relu(+bs[c=row])
// MODE 1: A=Y, B=Wf1t -> T bf16, relu(acc*EX[row]+bf1[col])
// MODE 2: A=T, B=Wf2t -> out f32, acc+bf2[col]+x[row][col]
// MODE 3: A=Wc3 (kseg-blocked), B=Hts rows c+kseg -> Y bf16 + SEpart sums
template<int MODE>
__global__ __launch_bounds__(256, 2) void gemm_pipe(
    const u16* __restrict__ A, const u16* __restrict__ Bt,
    const float* __restrict__ bias, const float* __restrict__ res,
    void* __restrict__ outv, u16* __restrict__ auxout,
    float* __restrict__ SEpart, const float* __restrict__ EX)
{
    constexpr int NK = (MODE == 2) ? 32 : (MODE == 3) ? 24 : 16;
    constexpr int SA = (MODE == 2) ? 1024 : 512;
    constexpr int SB = (MODE == 2) ? 1024 : 512;

    __shared__ u16 Asm[4 * 4096];     // 4 slots x 128 rows x 32 k  (32KB)
    __shared__ u16 Bsm[4 * 4096];     // 32KB

    const int tid = threadIdx.x;
    const int l   = tid & 63;
    const int w   = tid >> 6;
    const int nwg = gridDim.x;
    const int work = (blockIdx.x & 7) * (nwg >> 3) + (blockIdx.x >> 3);

    int row0, col0, bidx = 0;
    if (MODE == 0)      { row0 = (work >> 7) * 128; col0 = (work & 127) * 128; }
    else if (MODE == 1) { row0 = (work >> 3) * 128; col0 = (work & 7) * 128; }
    else if (MODE == 2) { row0 = (work >> 2) * 128; col0 = (work & 3) * 128; }
    else                { bidx = work >> 3; row0 = ((work >> 2) & 1) * 128;
                          col0 = (work & 3) * 128; }

    const u16* Aab  = A + (size_t)row0 * SA;
    const u16* Bab  = Bt + (size_t)col0 * SB;
    const u16* HtsB = Bt + (size_t)bidx * 514 * 256;

    const int wm = (w >> 1) * 64;
    const int wn = (w & 1) * 64;
    const int fr = l & 15;
    const int q  = l >> 4;
    const int kofs = ((q ^ ((l >> 1) & 3)) * 8);

    const f32x4 zero = {0.0f, 0.0f, 0.0f, 0.0f};
    f32x4 acc[4][4];
    #pragma unroll
    for (int m = 0; m < 4; ++m)
        #pragma unroll
        for (int n = 0; n < 4; ++n) acc[m][n] = zero;

    // staging: thread covers (row = tid>>2, 16B slot tid&3); pre-swizzled source
    const int kc0 = ((tid & 3) ^ ((tid >> 3) & 3)) * 8;
    const int srow = tid >> 2;          // 0..63

    auto stage = [&](int u, int slot) {
        u16* ald = Asm + slot * 4096 + w * 512;
        u16* bld = Bsm + slot * 4096 + w * 512;
        if (MODE == 3) {
            const int kseg = u >> 3, kb = (u & 7) * 32 + kc0;
            gll16(A + kseg * 65536 + (row0 + srow) * 256 + kb, ald);
            gll16(A + kseg * 65536 + (row0 + srow + 64) * 256 + kb, ald + 2048);
            gll16(HtsB + (size_t)(col0 + srow + kseg) * 256 + kb, bld);
            gll16(HtsB + (size_t)(col0 + srow + 64 + kseg) * 256 + kb, bld + 2048);
        } else {
            const int kb = u * 32 + kc0;
            gll16(Aab + (size_t)srow * SA + kb, ald);
            gll16(Aab + (size_t)(srow + 64) * SA + kb, ald + 2048);
            gll16(Bab + (size_t)srow * SB + kb, bld);
            gll16(Bab + (size_t)(srow + 64) * SB + kb, bld + 2048);
        }
    };

    stage(0, 0); stage(1, 1); stage(2, 2);
    for (int u = 0; u < NK; ++u) {
        if (u < NK - 2)       { VM8; }
        else if (u == NK - 2) { VM4; }
        else                  { VM0; }
        __builtin_amdgcn_s_barrier();
        MEMB;
        const int slot = u & 3;
        s16x8 bf4[4], af[4];
        #pragma unroll
        for (int n = 0; n < 4; ++n)
            bf4[n] = *(const s16x8*)&Bsm[slot * 4096 + (wn + n * 16 + fr) * 32 + kofs];
        #pragma unroll
        for (int m = 0; m < 4; ++m)
            af[m] = *(const s16x8*)&Asm[slot * 4096 + (wm + m * 16 + fr) * 32 + kofs];
        if (u + 3 < NK) stage(u + 3, (u + 3) & 3);
        __builtin_amdgcn_s_setprio(1);
        #pragma unroll
        for (int m = 0; m < 4; ++m)
            #pragma unroll
            for (int n = 0; n < 4; ++n)
                acc[m][n] = __builtin_amdgcn_mfma_f32_16x16x32_bf16(af[m], bf4[n], acc[m][n], 0, 0, 0);
        __builtin_amdgcn_s_setprio(0);
        MEMB;
    }

    if (MODE == 0) {
        // rows = c, cols = (b,ni); Hts[b][c+1+s(ni)][pi(ni)] = relu(acc+bs[c])
        const int gb = col0 + wn;
        const int b  = gb >> 8;
        const int gl = gb & 255;
        const int nib = gl + fr;
        u16* HtsW = auxout + (size_t)b * 514 * 256;
        const int px = gl + 4 * fr;
        const int s0 = shf(nib), s3 = shf(nib + 48);
        #pragma unroll
        for (int m = 0; m < 4; ++m) {
            #pragma unroll
            for (int j = 0; j < 4; ++j) {
                const int c = row0 + wm + m * 16 + q * 4 + j;
                const float bsv = bias[c];
                u16 vv[4];
                #pragma unroll
                for (int n = 0; n < 4; ++n)
                    vv[n] = f2b(fmaxf(acc[m][n][j] + bsv, 0.0f));
                if (s0 == s3) {
                    ushort4 v4 = {vv[0], vv[1], vv[2], vv[3]};
                    *(ushort4*)&HtsW[(size_t)(c + 1 + s0) * 256 + px] = v4;
                } else {
                    #pragma unroll
                    for (int n = 0; n < 4; ++n)
                        HtsW[(size_t)(c + 1 + shf(nib + n * 16)) * 256 + px + n] = vv[n];
                }
            }
        }
    } else if (MODE == 1) {
        const int cgb = col0 + wn;
        float bval[4];
        #pragma unroll
        for (int n = 0; n < 4; ++n) bval[n] = bias[cgb + n * 16 + fr];
        #pragma unroll
        for (int m = 0; m < 4; ++m) {
            #pragma unroll
            for (int j = 0; j < 4; ++j) {
                const int row = row0 + wm + m * 16 + q * 4 + j;
                const float sc = EX[row];
                u16 vv[4];
                #pragma unroll
                for (int n = 0; n < 4; ++n)
                    vv[n] = f2b(fmaxf(acc[m][n][j] * sc + bval[n], 0.0f));
                ushort4 v4 = {vv[0], vv[1], vv[2], vv[3]};
                *(ushort4*)&((u16*)outv)[(size_t)row * 1024 + cgb + 4 * fr] = v4;
            }
        }
    } else if (MODE == 2) {
        #pragma unroll
        for (int m = 0; m < 4; ++m) {
            #pragma unroll
            for (int j = 0; j < 4; ++j) {
                const int row = row0 + wm + m * 16 + q * 4 + j;
                #pragma unroll
                for (int n = 0; n < 4; ++n) {
                    const int col = col0 + wn + n * 16 + fr;
                    ((float*)outv)[(size_t)row * 512 + col] =
                        acc[m][n][j] + bias[col] + res[(size_t)row * 512 + col];
                }
            }
        }
    } else {
        // conv: rows = no, cols = c; Y[b][no][pi(c)]; SEpart per 64-col slot
        const int cb = col0 + wn;
        const int px = cb + 4 * fr;
        const int sslot = cb >> 6;         // 0..7
        #pragma unroll
        for (int m = 0; m < 4; ++m) {
            #pragma unroll
            for (int j = 0; j < 4; ++j) {
                const int no = row0 + wm + m * 16 + q * 4 + j;
                const float bcv = bias[no];
                float p = 0.0f;
                u16 vv[4];
                #pragma unroll
                for (int n = 0; n < 4; ++n) {
                    float v = acc[m][n][j];
                    vv[n] = f2b(v + bcv);
                    p += v;
                }
                ushort4 v4 = {vv[0], vv[1], vv[2], vv[3]};
                *(ushort4*)&auxout[((size_t)bidx * NN + no) * CCH + px] = v4;
                p += __shfl_xor(p, 1);
                p += __shfl_xor(p, 2);
                p += __shfl_xor(p, 4);
                p += __shfl_xor(p, 8);
                if (fr == 0)
                    SEpart[sslot * 16384 + bidx * NN + no] = p;
            }
        }
    }
}

// ---------------- SE MLP: EX = sigmoid(relu(se@We1+be1)@We2+be2) ----------------
__global__ __launch_bounds__(256) void semlp_kernel(const float* __restrict__ sep,
    const float* __restrict__ bc,
    const float* __restrict__ We1, const float* __restrict__ be1,
    const float* __restrict__ We2, const float* __restrict__ be2,
    float* __restrict__ ex)
{
    __shared__ float sse[256];
    __shared__ float e1[32];
    int b = blockIdx.x, t = threadIdx.x;
    int o = b * 256 + t;
    float sum = 0.0f;
    #pragma unroll
    for (int i = 0; i < 8; ++i) sum += sep[i * 16384 + o];
    sse[t] = sum * (1.0f / CCH) + bc[t];
    __syncthreads();
    if (t < 32) {
        float a = be1[t];
        #pragma unroll 8
        for (int i = 0; i < 256; ++i) a += sse[i] * We1[i * 32 + t];
        e1[t] = fmaxf(a, 0.0f);
    }
    __syncthreads();
    float a = be2[t];
    #pragma unroll
    for (int j = 0; j < 32; ++j) a += e1[j] * We2[j * 256 + t];
    ex[b * 256 + t] = 1.0f / (1.0f + expf(-a));
}

extern "C" void kernel_launch(void* const* d_in, const int* in_sizes, int n_in,
                              void* d_out, int out_size, void* d_ws, size_t ws_size,
                              hipStream_t stream) {
    const float* x    = (const float*)d_in[0];
    const float* ln_g = (const float*)d_in[1];
    const float* ln_b = (const float*)d_in[2];
    const float* Ws   = (const float*)d_in[3];
    const float* bs   = (const float*)d_in[4];
    const float* Wc   = (const float*)d_in[5];
    const float* bc   = (const float*)d_in[6];
    const float* We1  = (const float*)d_in[7];
    const float* be1  = (const float*)d_in[8];
    const float* We2  = (const float*)d_in[9];
    const float* be2  = (const float*)d_in[10];
    const float* Wf1  = (const float*)d_in[11];
    const float* bf1  = (const float*)d_in[12];
    const float* Wf2  = (const float*)d_in[13];
    const float* bf2  = (const float*)d_in[14];
    float* out = (float*)d_out;
    char* w8   = (char*)d_ws;

    // workspace (r9 overlay layout, proven):
    //   [0,16M)      XN bf16 16384x512, reused as Y after gemm0
    //   [16M,~33M)   Hts bf16 64x514x256 (dead after conv)
    //   [16M,48M)    T bf16 16384x1024 (overlays Hts)
    //   [48.06M..]   tail: SEpart, Wst, Wf1t, Wf2t, Wc3, EX
    u16* XN  = (u16*)(w8);
    u16* Y   = XN;
    u16* Hts = (u16*)(w8 + (16u << 20));
    u16* T   = (u16*)(w8 + (16u << 20));
    char* tail = w8 + 50397184;
    float* SEpart = (float*)(tail);                 // 512K [8][64][256]
    u16* Wst      = (u16*)(tail + 524288);          // 512K
    u16* Wf1t     = (u16*)(tail + 1048576);         // 1M
    u16* Wf2t     = (u16*)(tail + 2097152);         // 1M
    u16* Wc3      = (u16*)(tail + 3145728);         // 384K
    float* EX     = (float*)(tail + 3538944);       // 64K

    prep_ln_kernel<<<6400, 256, 0, stream>>>(Ws, Wst, Wf1, Wf1t, Wf2, Wf2t,
                                             Wc, Wc3, Hts, x, ln_g, ln_b, XN);
    // Hts = shifted-transpose(relu(Ws^T @ XN^T + bs)), ni pi-permuted
    gemm_pipe<0><<<512, 256, 0, stream>>>(Wst, XN, bs, nullptr,
        nullptr, Hts, nullptr, nullptr);
    // Y = conv1d(shift(H)) + bc (c pi-permuted); SEpart partial row-sums
    gemm_pipe<3><<<512, 256, 0, stream>>>(Wc3, Hts, bc, nullptr,
        nullptr, Y, SEpart, nullptr);
    // EX = sigmoid(MLP(se))
    semlp_kernel<<<BB, 256, 0, stream>>>(SEpart, bc, We1, be1, We2, be2, EX);
    // T = relu((Y*ex) @ Wf1 + bf1), col pi-permuted
    gemm_pipe<1><<<1024, 256, 0, stream>>>(Y, Wf1t, bf1, nullptr,
        T, nullptr, nullptr, EX);
    // out = T @ Wf2 + bf2 + x
    gemm_pipe<2><<<512, 256, 0, stream>>>(T, Wf2t, bf2, x,
        out, nullptr, nullptr, nullptr);
}

// Round 13
// 116.810 us; speedup vs baseline: 2.5110x; 1.0061x over previous
//
#include <hip/hip_runtime.h>
#include <hip/hip_bf16.h>
#include <math.h>

#define BB 64
#define NN 256
#define CCH 512

typedef unsigned short u16;
typedef __attribute__((ext_vector_type(8))) short s16x8;
typedef __attribute__((ext_vector_type(4))) float f32x4;

#define AS1 __attribute__((address_space(1)))
#define AS3 __attribute__((address_space(3)))

static __device__ __forceinline__ u16 f2b(float f) {
    __hip_bfloat16 h = __float2bfloat16(f);
    union { __hip_bfloat16 h; u16 u; } x; x.h = h; return x.u;
}
static __device__ __forceinline__ void gll16(const void* g, void* l) {
    __builtin_amdgcn_global_load_lds((const AS1 unsigned int*)g,
                                     (AS3 unsigned int*)l, 16, 0, 0);
}
static __device__ __forceinline__ int shf(int ni) {
    return (ni < 86) ? -1 : (ni < 172 ? 0 : 1);
}

#define VM6  asm volatile("s_waitcnt vmcnt(6)" ::: "memory")
#define VM0  asm volatile("s_waitcnt vmcnt(0)" ::: "memory")
#define MEMB asm volatile("" ::: "memory")

// ---------------- merged prep (weights, Hts edges) + LayerNorm ----------------
// k-permutation: stored location = (k & ~63) | ((k&15)<<2) | ((k>>4)&3)
static __device__ __forceinline__ void wtc_body(const float* __restrict__ W,
    u16* __restrict__ Wt, int K, int N, int bx, int by, float* t, bool perm)
{
    int n0 = bx * 32, k0 = by * 32;
    int tx = threadIdx.x & 31, ty = threadIdx.x >> 5;
    #pragma unroll
    for (int i = 0; i < 4; ++i)
        t[(ty + i * 8) * 33 + tx] = W[(size_t)(k0 + ty + i * 8) * N + n0 + tx];
    __syncthreads();
    int kl = k0 + tx;
    int kp = perm ? ((kl & ~63) | ((kl & 15) << 2) | ((kl >> 4) & 3)) : kl;
    #pragma unroll
    for (int i = 0; i < 4; ++i)
        Wt[(size_t)(n0 + ty + i * 8) * K + kp] = f2b(t[tx * 33 + ty + i * 8]);
}

__global__ __launch_bounds__(256) void prep_ln_kernel(
    const float* __restrict__ Ws,  u16* __restrict__ Wst,
    const float* __restrict__ Wf1, u16* __restrict__ Wf1t,
    const float* __restrict__ Wf2, u16* __restrict__ Wf2t,
    const float* __restrict__ Wc,  u16* __restrict__ Wc3,
    u16* __restrict__ Hts,
    const float* __restrict__ x, const float* __restrict__ g,
    const float* __restrict__ bta, u16* __restrict__ xnorm)
{
    __shared__ float t[32 * 33];
    int bid = blockIdx.x;
    if (bid < 256) {                       // Ws -> Wst (no perm)
        wtc_body(Ws, Wst, 512, 512, bid & 15, bid >> 4, t, false);
    } else if (bid < 768) {                // Wf1 -> Wf1t [1024][512-perm]
        int idx = bid - 256;
        wtc_body(Wf1, Wf1t, 512, 1024, idx & 31, idx >> 5, t, true);
    } else if (bid < 1280) {               // Wf2 -> Wf2t [512][1024-perm]
        int idx = bid - 768;
        wtc_body(Wf2, Wf2t, 1024, 512, idx & 15, idx >> 4, t, true);
    } else if (bid < 2048) {               // Wc3[k][o][ni-perm]
        int idx = (bid - 1280) * 256 + threadIdx.x;
        int xloc = idx & 255;
        int o = (idx >> 8) & 255;
        int k = idx >> 16;
        int il = (xloc & ~63) | ((xloc & 63) >> 2) | ((xloc & 3) << 4);
        Wc3[idx] = f2b(Wc[((size_t)o * NN + il) * 3 + k]);
    } else if (bid < 2304) {               // zero Hts edge rows {0,1,512,513}
        int idx = (bid - 2048) * 256 + threadIdx.x;
        int b   = idx >> 10;
        int rem = idx & 1023;
        int rr  = rem >> 8;
        int r   = (rr & 1) + (rr >> 1) * 512;
        Hts[((size_t)b * 514 + r) * 256 + (rem & 255)] = 0;
    } else {                               // LayerNorm, one wave per row
        const int l = threadIdx.x & 63;
        const int r = (bid - 2304) * 4 + (threadIdx.x >> 6);
        const float4* xr = (const float4*)(x + (size_t)r * CCH);
        float4 v1 = xr[l];
        float4 v2 = xr[l + 64];
        float s  = v1.x + v1.y + v1.z + v1.w + v2.x + v2.y + v2.z + v2.w;
        float ss = v1.x*v1.x + v1.y*v1.y + v1.z*v1.z + v1.w*v1.w
                 + v2.x*v2.x + v2.y*v2.y + v2.z*v2.z + v2.w*v2.w;
        #pragma unroll
        for (int o = 32; o > 0; o >>= 1) {
            s  += __shfl_xor(s, o);
            ss += __shfl_xor(ss, o);
        }
        float mu  = s * (1.0f / CCH);
        float var = ss * (1.0f / CCH) - mu * mu;
        float rs  = rsqrtf(var + 1e-5f);
        float4 g1 = ((const float4*)g)[l],   g2 = ((const float4*)g)[l + 64];
        float4 b1 = ((const float4*)bta)[l], b2 = ((const float4*)bta)[l + 64];
        ushort4 o1, o2;
        o1.x = f2b((v1.x - mu) * rs * g1.x + b1.x);
        o1.y = f2b((v1.y - mu) * rs * g1.y + b1.y);
        o1.z = f2b((v1.z - mu) * rs * g1.z + b1.z);
        o1.w = f2b((v1.w - mu) * rs * g1.w + b1.w);
        o2.x = f2b((v2.x - mu) * rs * g2.x + b2.x);
        o2.y = f2b((v2.y - mu) * rs * g2.y + b2.y);
        o2.z = f2b((v2.z - mu) * rs * g2.z + b2.z);
        o2.w = f2b((v2.w - mu) * rs * g2.w + b2.w);
        ushort4* orow = (ushort4*)(xnorm + (size_t)r * CCH);
        orow[l]      = o1;
        orow[l + 64] = o2;
    }
}

// ---------------- 6-slot pipelined GEMM core (modes 0, 2, 3; BN=128) ----------------
// r9-proven: 8 waves, 64x64 wave tiles (4Mx2N), pi-permuted ushort4 stores.
template<int MODE>
__global__ __launch_bounds__(512, 1) void gemm_pipe(
    const u16* __restrict__ A, const u16* __restrict__ Bt,
    const float* __restrict__ bias, const float* __restrict__ res,
    void* __restrict__ outv, u16* __restrict__ auxout,
    float* __restrict__ SEpart)
{
    constexpr int NK = (MODE == 2) ? 32 : (MODE == 3) ? 24 : 16;
    constexpr int SA = (MODE == 2) ? 1024 : 512;
    constexpr int SB = (MODE == 2) ? 1024 : 512;

    __shared__ u16 Asm[6 * 8192];
    __shared__ u16 Bsm[6 * 4096];

    const int tid = threadIdx.x;
    const int l   = tid & 63;
    const int w   = tid >> 6;
    const int nwg = gridDim.x;
    const int work = (blockIdx.x & 7) * (nwg >> 3) + (blockIdx.x >> 3);

    int row0, col0, bidx = 0;
    if (MODE == 0)      { row0 = (work >> 7) * 256; col0 = (work & 127) * 128; }
    else if (MODE == 2) { row0 = (work >> 2) * 256; col0 = (work & 3) * 128; }
    else                { row0 = 0; bidx = work >> 2; col0 = (work & 3) * 128; }

    const u16* Aab  = A + (size_t)row0 * SA;
    const u16* Bab  = Bt + (size_t)col0 * SB;
    const u16* HtsB = Bt + (size_t)bidx * 514 * 256;

    const int wm = (w >> 1) * 64;
    const int wn = (w & 1) * 64;
    const int fr = l & 15;
    const int q  = l >> 4;
    const int kofs = ((q ^ ((l >> 1) & 3)) * 8);

    const f32x4 zero = {0.0f, 0.0f, 0.0f, 0.0f};
    f32x4 acc[4][4];
    #pragma unroll
    for (int m = 0; m < 4; ++m)
        #pragma unroll
        for (int n = 0; n < 4; ++n) acc[m][n] = zero;

    const int kc0 = ((tid & 3) ^ ((tid >> 3) & 3)) * 8;
    const int srow = tid >> 2;

    auto stage = [&](int u, int slot) {
        u16* ald = Asm + slot * 8192 + w * 512;
        u16* bld = Bsm + slot * 4096 + w * 512;
        if (MODE == 3) {
            const int kseg = u >> 3, kb = (u & 7) * 32 + kc0;
            gll16(A + kseg * 65536 + srow * 256 + kb, ald);
            gll16(A + kseg * 65536 + (srow + 128) * 256 + kb, ald + 4096);
            gll16(HtsB + (size_t)(col0 + srow + kseg) * 256 + kb, bld);
        } else {
            const int kb = u * 32 + kc0;
            gll16(Aab + (size_t)srow * SA + kb, ald);
            gll16(Aab + (size_t)(srow + 128) * SA + kb, ald + 4096);
            gll16(Bab + (size_t)srow * SB + kb, bld);
        }
    };

    stage(0, 0); stage(1, 1); stage(2, 2); stage(3, 3);
    int sa = 0;
    constexpr int NV = NK / 2;
    for (int v = 0; v < NV; ++v) {
        if (v + 1 < NV) { VM6; } else { VM0; }
        __builtin_amdgcn_s_barrier();
        MEMB;
        const int sb = sa + 1;
        s16x8 b0[4], af0[4];
        #pragma unroll
        for (int n = 0; n < 4; ++n)
            b0[n] = *(const s16x8*)&Bsm[sa * 4096 + (wn + n * 16 + fr) * 32 + kofs];
        #pragma unroll
        for (int m = 0; m < 4; ++m)
            af0[m] = *(const s16x8*)&Asm[sa * 8192 + (wm + m * 16 + fr) * 32 + kofs];
        const int u2 = 2 * v + 4;
        if (u2 < NK) {
            int st = sa + 4; if (st >= 6) st -= 6;
            stage(u2, st);
            int st1 = st + 1; if (st1 >= 6) st1 -= 6;
            stage(u2 + 1, st1);
        }
        __builtin_amdgcn_s_setprio(1);
        #pragma unroll
        for (int m = 0; m < 4; ++m)
            #pragma unroll
            for (int n = 0; n < 4; ++n)
                acc[m][n] = __builtin_amdgcn_mfma_f32_16x16x32_bf16(af0[m], b0[n], acc[m][n], 0, 0, 0);
        __builtin_amdgcn_s_setprio(0);
        s16x8 b1[4], af1[4];
        #pragma unroll
        for (int n = 0; n < 4; ++n)
            b1[n] = *(const s16x8*)&Bsm[sb * 4096 + (wn + n * 16 + fr) * 32 + kofs];
        #pragma unroll
        for (int m = 0; m < 4; ++m)
            af1[m] = *(const s16x8*)&Asm[sb * 8192 + (wm + m * 16 + fr) * 32 + kofs];
        __builtin_amdgcn_s_setprio(1);
        #pragma unroll
        for (int m = 0; m < 4; ++m)
            #pragma unroll
            for (int n = 0; n < 4; ++n)
                acc[m][n] = __builtin_amdgcn_mfma_f32_16x16x32_bf16(af1[m], b1[n], acc[m][n], 0, 0, 0);
        __builtin_amdgcn_s_setprio(0);
        MEMB;
        sa += 2; if (sa >= 6) sa = 0;
    }

    if (MODE == 0) {
        // rows = c, cols = (b,ni); Hts[b][c+1+s(ni)][pi(ni)] = relu(acc+bs[c])
        const int gb = col0 + wn;
        const int b  = gb >> 8;
        const int gl = gb & 255;
        const int nib = gl + fr;
        u16* HtsW = auxout + (size_t)b * 514 * 256;
        const int px = gl + 4 * fr;
        const int s0 = shf(nib), s3 = shf(nib + 48);
        #pragma unroll
        for (int m = 0; m < 4; ++m) {
            #pragma unroll
            for (int j = 0; j < 4; ++j) {
                const int c = row0 + wm + m * 16 + q * 4 + j;
                const float bsv = bias[c];
                u16 vv[4];
                #pragma unroll
                for (int n = 0; n < 4; ++n)
                    vv[n] = f2b(fmaxf(acc[m][n][j] + bsv, 0.0f));
                if (s0 == s3) {
                    ushort4 v4 = {vv[0], vv[1], vv[2], vv[3]};
                    *(ushort4*)&HtsW[(size_t)(c + 1 + s0) * 256 + px] = v4;
                } else {
                    #pragma unroll
                    for (int n = 0; n < 4; ++n)
                        HtsW[(size_t)(c + 1 + shf(nib + n * 16)) * 256 + px + n] = vv[n];
                }
            }
        }
    } else if (MODE == 2) {
        #pragma unroll
        for (int m = 0; m < 4; ++m) {
            #pragma unroll
            for (int j = 0; j < 4; ++j) {
                const int row = row0 + wm + m * 16 + q * 4 + j;
                #pragma unroll
                for (int n = 0; n < 4; ++n) {
                    const int col = col0 + wn + n * 16 + fr;
                    ((float*)outv)[(size_t)row * 512 + col] =
                        acc[m][n][j] + bias[col] + res[(size_t)row * 512 + col];
                }
            }
        }
    } else {
        // conv: rows = no, cols = c; Y[b][no][pi(c)]; SEpart per (ct,wn) slot
        const int cb = col0 + wn;
        const int px = cb + 4 * fr;
        const int sslot = (col0 >> 7) * 2 + (wn >> 6);   // 0..7
        #pragma unroll
        for (int m = 0; m < 4; ++m) {
            #pragma unroll
            for (int j = 0; j < 4; ++j) {
                const int no = wm + m * 16 + q * 4 + j;
                const float bcv = bias[no];
                float p = 0.0f;
                u16 vv[4];
                #pragma unroll
                for (int n = 0; n < 4; ++n) {
                    float v = acc[m][n][j];
                    vv[n] = f2b(v + bcv);
                    p += v;
                }
                ushort4 v4 = {vv[0], vv[1], vv[2], vv[3]};
                *(ushort4*)&auxout[((size_t)bidx * NN + no) * CCH + px] = v4;
                p += __shfl_xor(p, 1);
                p += __shfl_xor(p, 2);
                p += __shfl_xor(p, 4);
                p += __shfl_xor(p, 8);
                if (fr == 0)
                    SEpart[sslot * 16384 + bidx * NN + no] = p;
            }
        }
    }
}

// ---------------- gemm1: high-occupancy 2-phase, 128x128, 4 waves, 4 blk/CU ----------------
// T = relu((Y*ex) @ Wf1 + bf1), col pi-permuted. 2-slot LDS (32KB), 16 waves/CU.
__global__ __launch_bounds__(256, 4) void gemm1_hi(
    const u16* __restrict__ Yb, const u16* __restrict__ Wf1t,
    const float* __restrict__ bf1, u16* __restrict__ T,
    const float* __restrict__ EX)
{
    __shared__ u16 Asm[2 * 4096];     // 2 slots x 128 rows x 32 k
    __shared__ u16 Bsm[2 * 4096];

    const int tid = threadIdx.x;
    const int l   = tid & 63;
    const int w   = tid >> 6;
    const int work = (blockIdx.x & 7) * 128 + (blockIdx.x >> 3);   // nwg=1024
    const int row0 = (work >> 3) * 128;
    const int col0 = (work & 7) * 128;

    const u16* Aab = Yb   + (size_t)row0 * 512;
    const u16* Bab = Wf1t + (size_t)col0 * 512;

    const int wm = (w >> 1) * 64;
    const int wn = (w & 1) * 64;
    const int fr = l & 15;
    const int q  = l >> 4;
    const int kofs = ((q ^ ((l >> 1) & 3)) * 8);

    const f32x4 zero = {0.0f, 0.0f, 0.0f, 0.0f};
    f32x4 acc[4][4];
    #pragma unroll
    for (int m = 0; m < 4; ++m)
        #pragma unroll
        for (int n = 0; n < 4; ++n) acc[m][n] = zero;

    const int kc0 = ((tid & 3) ^ ((tid >> 3) & 3)) * 8;
    const int srow = tid >> 2;

    auto stage = [&](int u, int slot) {
        u16* ald = Asm + slot * 4096 + w * 512;
        u16* bld = Bsm + slot * 4096 + w * 512;
        const int kb = u * 32 + kc0;
        gll16(Aab + (size_t)srow * 512 + kb, ald);
        gll16(Aab + (size_t)(srow + 64) * 512 + kb, ald + 2048);
        gll16(Bab + (size_t)srow * 512 + kb, bld);
        gll16(Bab + (size_t)(srow + 64) * 512 + kb, bld + 2048);
    };

    // T3-minimum 2-phase: stage(next) -> read(cur) -> MFMA -> vmcnt(0)+barrier
    stage(0, 0);
    VM0;
    __builtin_amdgcn_s_barrier();
    for (int u = 0; u < 16; ++u) {
        const int slot = u & 1;
        if (u + 1 < 16) stage(u + 1, slot ^ 1);
        s16x8 bf4[4], af[4];
        #pragma unroll
        for (int n = 0; n < 4; ++n)
            bf4[n] = *(const s16x8*)&Bsm[slot * 4096 + (wn + n * 16 + fr) * 32 + kofs];
        #pragma unroll
        for (int m = 0; m < 4; ++m)
            af[m] = *(const s16x8*)&Asm[slot * 4096 + (wm + m * 16 + fr) * 32 + kofs];
        __builtin_amdgcn_s_setprio(1);
        #pragma unroll
        for (int m = 0; m < 4; ++m)
            #pragma unroll
            for (int n = 0; n < 4; ++n)
                acc[m][n] = __builtin_amdgcn_mfma_f32_16x16x32_bf16(af[m], bf4[n], acc[m][n], 0, 0, 0);
        __builtin_amdgcn_s_setprio(0);
        MEMB;
        VM0;
        __builtin_amdgcn_s_barrier();
    }

    // epilogue: pi-permuted ushort4 stores, SE scale from EX
    const int cgb = col0 + wn;
    float bval[4];
    #pragma unroll
    for (int n = 0; n < 4; ++n) bval[n] = bf1[cgb + n * 16 + fr];
    #pragma unroll
    for (int m = 0; m < 4; ++m) {
        #pragma unroll
        for (int j = 0; j < 4; ++j) {
            const int row = row0 + wm + m * 16 + q * 4 + j;
            const float sc = EX[row];
            u16 vv[4];
            #pragma unroll
            for (int n = 0; n < 4; ++n)
                vv[n] = f2b(fmaxf(acc[m][n][j] * sc + bval[n], 0.0f));
            ushort4 v4 = {vv[0], vv[1], vv[2], vv[3]};
            *(ushort4*)&T[(size_t)row * 1024 + cgb + 4 * fr] = v4;
        }
    }
}

// ---------------- SE MLP: EX = sigmoid(relu(se@We1+be1)@We2+be2) ----------------
__global__ __launch_bounds__(256) void semlp_kernel(const float* __restrict__ sep,
    const float* __restrict__ bc,
    const float* __restrict__ We1, const float* __restrict__ be1,
    const float* __restrict__ We2, const float* __restrict__ be2,
    float* __restrict__ ex)
{
    __shared__ float sse[256];
    __shared__ float e1[32];
    int b = blockIdx.x, t = threadIdx.x;
    int o = b * 256 + t;
    float sum = 0.0f;
    #pragma unroll
    for (int i = 0; i < 8; ++i) sum += sep[i * 16384 + o];
    sse[t] = sum * (1.0f / CCH) + bc[t];
    __syncthreads();
    if (t < 32) {
        float a = be1[t];
        #pragma unroll 8
        for (int i = 0; i < 256; ++i) a += sse[i] * We1[i * 32 + t];
        e1[t] = fmaxf(a, 0.0f);
    }
    __syncthreads();
    float a = be2[t];
    #pragma unroll
    for (int j = 0; j < 32; ++j) a += e1[j] * We2[j * 256 + t];
    ex[b * 256 + t] = 1.0f / (1.0f + expf(-a));
}

extern "C" void kernel_launch(void* const* d_in, const int* in_sizes, int n_in,
                              void* d_out, int out_size, void* d_ws, size_t ws_size,
                              hipStream_t stream) {
    const float* x    = (const float*)d_in[0];
    const float* ln_g = (const float*)d_in[1];
    const float* ln_b = (const float*)d_in[2];
    const float* Ws   = (const float*)d_in[3];
    const float* bs   = (const float*)d_in[4];
    const float* Wc   = (const float*)d_in[5];
    const float* bc   = (const float*)d_in[6];
    const float* We1  = (const float*)d_in[7];
    const float* be1  = (const float*)d_in[8];
    const float* We2  = (const float*)d_in[9];
    const float* be2  = (const float*)d_in[10];
    const float* Wf1  = (const float*)d_in[11];
    const float* bf1  = (const float*)d_in[12];
    const float* Wf2  = (const float*)d_in[13];
    const float* bf2  = (const float*)d_in[14];
    float* out = (float*)d_out;
    char* w8   = (char*)d_ws;

    // workspace (r9 overlay layout, proven):
    //   [0,16M)      XN bf16 16384x512, reused as Y after gemm0
    //   [16M,~33M)   Hts bf16 64x514x256 (dead after conv)
    //   [16M,48M)    T bf16 16384x1024 (overlays Hts)
    //   [48.06M..]   tail: SEpart, Wst, Wf1t, Wf2t, Wc3, EX
    u16* XN  = (u16*)(w8);
    u16* Y   = XN;
    u16* Hts = (u16*)(w8 + (16u << 20));
    u16* T   = (u16*)(w8 + (16u << 20));
    char* tail = w8 + 50397184;
    float* SEpart = (float*)(tail);                 // 512K [8][64][256]
    u16* Wst      = (u16*)(tail + 524288);          // 512K
    u16* Wf1t     = (u16*)(tail + 1048576);         // 1M
    u16* Wf2t     = (u16*)(tail + 2097152);         // 1M
    u16* Wc3      = (u16*)(tail + 3145728);         // 384K
    float* EX     = (float*)(tail + 3538944);       // 64K

    prep_ln_kernel<<<6400, 256, 0, stream>>>(Ws, Wst, Wf1, Wf1t, Wf2, Wf2t,
                                             Wc, Wc3, Hts, x, ln_g, ln_b, XN);
    // Hts = shifted-transpose(relu(Ws^T @ XN^T + bs)), ni pi-permuted
    gemm_pipe<0><<<256, 512, 0, stream>>>(Wst, XN, bs, nullptr,
                                          nullptr, Hts, nullptr);
    // Y = conv1d(shift(H)) + bc (c pi-permuted); SEpart partial row-sums
    gemm_pipe<3><<<256, 512, 0, stream>>>(Wc3, Hts, bc, nullptr,
                                          nullptr, Y, SEpart);
    // EX = sigmoid(MLP(se))
    semlp_kernel<<<BB, 256, 0, stream>>>(SEpart, bc, We1, be1, We2, be2, EX);
    // T = relu((Y*ex) @ Wf1 + bf1)  [high-occupancy 2-phase, 4 blk/CU]
    gemm1_hi<<<1024, 256, 0, stream>>>(Y, Wf1t, bf1, T, EX);
    // out = T @ Wf2 + bf2 + x
    gemm_pipe<2><<<256, 512, 0, stream>>>(T, Wf2t, bf2, x,
                                          out, nullptr, nullptr);
}

// Round 14
// 114.367 us; speedup vs baseline: 2.5646x; 1.0214x over previous
//
#include <hip/hip_runtime.h>
#include <hip/hip_bf16.h>
#include <math.h>

#define BB 64
#define NN 256
#define CCH 512

typedef unsigned short u16;
typedef __attribute__((ext_vector_type(8))) short s16x8;
typedef __attribute__((ext_vector_type(4))) float f32x4;

#define AS1 __attribute__((address_space(1)))
#define AS3 __attribute__((address_space(3)))

static __device__ __forceinline__ u16 f2b(float f) {
    __hip_bfloat16 h = __float2bfloat16(f);
    union { __hip_bfloat16 h; u16 u; } x; x.h = h; return x.u;
}
static __device__ __forceinline__ void gll16(const void* g, void* l) {
    __builtin_amdgcn_global_load_lds((const AS1 unsigned int*)g,
                                     (AS3 unsigned int*)l, 16, 0, 0);
}
static __device__ __forceinline__ int shf(int ni) {
    return (ni < 86) ? -1 : (ni < 172 ? 0 : 1);
}

#define VM8  asm volatile("s_waitcnt vmcnt(8)" ::: "memory")
#define VM6  asm volatile("s_waitcnt vmcnt(6)" ::: "memory")
#define VM0  asm volatile("s_waitcnt vmcnt(0)" ::: "memory")
#define LGKM0 asm volatile("s_waitcnt lgkmcnt(0)" ::: "memory")
#define MEMB asm volatile("" ::: "memory")

// ---------------- merged prep (weights, Hts edges) + LayerNorm ----------------
// k-permutation: stored location x = (k & ~63) | ((k&15)<<2) | ((k>>4)&3)
static __device__ __forceinline__ void wtc_body(const float* __restrict__ W,
    u16* __restrict__ Wt, int K, int N, int bx, int by, float* t, bool perm)
{
    int n0 = bx * 32, k0 = by * 32;
    int tx = threadIdx.x & 31, ty = threadIdx.x >> 5;
    #pragma unroll
    for (int i = 0; i < 4; ++i)
        t[(ty + i * 8) * 33 + tx] = W[(size_t)(k0 + ty + i * 8) * N + n0 + tx];
    __syncthreads();
    int kl = k0 + tx;
    int kp = perm ? ((kl & ~63) | ((kl & 15) << 2) | ((kl >> 4) & 3)) : kl;
    #pragma unroll
    for (int i = 0; i < 4; ++i)
        Wt[(size_t)(n0 + ty + i * 8) * K + kp] = f2b(t[tx * 33 + ty + i * 8]);
}

__global__ __launch_bounds__(256) void prep_ln_kernel(
    const float* __restrict__ Ws,  u16* __restrict__ Wst,
    const float* __restrict__ Wf1, u16* __restrict__ Wf1t,
    const float* __restrict__ Wf2, u16* __restrict__ Wf2t,
    const float* __restrict__ Wc,  u16* __restrict__ Wc3,
    u16* __restrict__ Hts,
    const float* __restrict__ x, const float* __restrict__ g,
    const float* __restrict__ bta, u16* __restrict__ xnorm)
{
    __shared__ float t[32 * 33];
    int bid = blockIdx.x;
    if (bid < 256) {                       // Ws -> Wst (no perm)
        wtc_body(Ws, Wst, 512, 512, bid & 15, bid >> 4, t, false);
    } else if (bid < 768) {                // Wf1 -> Wf1t [1024][512-perm]
        int idx = bid - 256;
        wtc_body(Wf1, Wf1t, 512, 1024, idx & 31, idx >> 5, t, true);
    } else if (bid < 1280) {               // Wf2 -> Wf2t [512][1024-perm]
        int idx = bid - 768;
        wtc_body(Wf2, Wf2t, 1024, 512, idx & 15, idx >> 4, t, true);
    } else if (bid < 2048) {               // Wc3[k][o][ni-perm]
        int idx = (bid - 1280) * 256 + threadIdx.x;
        int xloc = idx & 255;
        int o = (idx >> 8) & 255;
        int k = idx >> 16;
        int il = (xloc & ~63) | ((xloc & 63) >> 2) | ((xloc & 3) << 4);
        Wc3[idx] = f2b(Wc[((size_t)o * NN + il) * 3 + k]);
    } else if (bid < 2304) {               // zero Hts edge rows {0,1,512,513}
        int idx = (bid - 2048) * 256 + threadIdx.x;
        int b   = idx >> 10;
        int rem = idx & 1023;
        int rr  = rem >> 8;
        int r   = (rr & 1) + (rr >> 1) * 512;
        Hts[((size_t)b * 514 + r) * 256 + (rem & 255)] = 0;
    } else {                               // LayerNorm, one wave per row
        const int l = threadIdx.x & 63;
        const int r = (bid - 2304) * 4 + (threadIdx.x >> 6);
        const float4* xr = (const float4*)(x + (size_t)r * CCH);
        float4 v1 = xr[l];
        float4 v2 = xr[l + 64];
        float s  = v1.x + v1.y + v1.z + v1.w + v2.x + v2.y + v2.z + v2.w;
        float ss = v1.x*v1.x + v1.y*v1.y + v1.z*v1.z + v1.w*v1.w
                 + v2.x*v2.x + v2.y*v2.y + v2.z*v2.z + v2.w*v2.w;
        #pragma unroll
        for (int o = 32; o > 0; o >>= 1) {
            s  += __shfl_xor(s, o);
            ss += __shfl_xor(ss, o);
        }
        float mu  = s * (1.0f / CCH);
        float var = ss * (1.0f / CCH) - mu * mu;
        float rs  = rsqrtf(var + 1e-5f);
        float4 g1 = ((const float4*)g)[l],   g2 = ((const float4*)g)[l + 64];
        float4 b1 = ((const float4*)bta)[l], b2 = ((const float4*)bta)[l + 64];
        ushort4 o1, o2;
        o1.x = f2b((v1.x - mu) * rs * g1.x + b1.x);
        o1.y = f2b((v1.y - mu) * rs * g1.y + b1.y);
        o1.z = f2b((v1.z - mu) * rs * g1.z + b1.z);
        o1.w = f2b((v1.w - mu) * rs * g1.w + b1.w);
        o2.x = f2b((v2.x - mu) * rs * g2.x + b2.x);
        o2.y = f2b((v2.y - mu) * rs * g2.y + b2.y);
        o2.z = f2b((v2.z - mu) * rs * g2.z + b2.z);
        o2.w = f2b((v2.w - mu) * rs * g2.w + b2.w);
        ushort4* orow = (ushort4*)(xnorm + (size_t)r * CCH);
        orow[l]      = o1;
        orow[l + 64] = o2;
    }
}

// ---------------- 6-slot pipelined GEMM core (modes 0, 2, 3; BN=128) ----------------
// 64x64 wave tiles (4Mx2N), pi-permuted ushort4 epilogue stores.
template<int MODE>
__global__ __launch_bounds__(512, 1) void gemm_pipe(
    const u16* __restrict__ A, const u16* __restrict__ Bt,
    const float* __restrict__ bias, const float* __restrict__ res,
    void* __restrict__ outv, u16* __restrict__ auxout,
    float* __restrict__ SEpart)
{
    constexpr int NK = (MODE == 2) ? 32 : (MODE == 3) ? 24 : 16;
    constexpr int SA = (MODE == 2) ? 1024 : 512;
    constexpr int SB = (MODE == 2) ? 1024 : 512;

    __shared__ u16 Asm[6 * 8192];
    __shared__ u16 Bsm[6 * 4096];

    const int tid = threadIdx.x;
    const int l   = tid & 63;
    const int w   = tid >> 6;
    const int nwg = gridDim.x;
    const int work = (blockIdx.x & 7) * (nwg >> 3) + (blockIdx.x >> 3);

    int row0, col0, bidx = 0;
    if (MODE == 0)      { row0 = (work >> 7) * 256; col0 = (work & 127) * 128; }
    else if (MODE == 2) { row0 = (work >> 2) * 256; col0 = (work & 3) * 128; }
    else                { row0 = 0; bidx = work >> 2; col0 = (work & 3) * 128; }

    const u16* Aab  = A + (size_t)row0 * SA;
    const u16* Bab  = Bt + (size_t)col0 * SB;
    const u16* HtsB = Bt + (size_t)bidx * 514 * 256;

    const int wm = (w >> 1) * 64;          // 4 M-groups of 64
    const int wn = (w & 1) * 64;           // 2 N-groups of 64
    const int fr = l & 15;
    const int q  = l >> 4;
    const int kofs = ((q ^ ((l >> 1) & 3)) * 8);

    const f32x4 zero = {0.0f, 0.0f, 0.0f, 0.0f};
    f32x4 acc[4][4];
    #pragma unroll
    for (int m = 0; m < 4; ++m)
        #pragma unroll
        for (int n = 0; n < 4; ++n) acc[m][n] = zero;

    const int kc0 = ((tid & 3) ^ ((tid >> 3) & 3)) * 8;
    const int srow = tid >> 2;

    auto stage = [&](int u, int slot) {
        u16* ald = Asm + slot * 8192 + w * 512;
        u16* bld = Bsm + slot * 4096 + w * 512;
        if (MODE == 3) {
            const int kseg = u >> 3, kb = (u & 7) * 32 + kc0;
            gll16(A + kseg * 65536 + srow * 256 + kb, ald);
            gll16(A + kseg * 65536 + (srow + 128) * 256 + kb, ald + 4096);
            gll16(HtsB + (size_t)(col0 + srow + kseg) * 256 + kb, bld);
        } else {
            const int kb = u * 32 + kc0;
            gll16(Aab + (size_t)srow * SA + kb, ald);
            gll16(Aab + (size_t)(srow + 128) * SA + kb, ald + 4096);
            gll16(Bab + (size_t)srow * SB + kb, bld);
        }
    };

    stage(0, 0); stage(1, 1); stage(2, 2); stage(3, 3);
    int sa = 0;
    constexpr int NV = NK / 2;
    for (int v = 0; v < NV; ++v) {
        if (v + 1 < NV) { VM6; } else { VM0; }
        __builtin_amdgcn_s_barrier();
        MEMB;
        const int sb = sa + 1;
        s16x8 b0[4], af0[4];
        #pragma unroll
        for (int n = 0; n < 4; ++n)
            b0[n] = *(const s16x8*)&Bsm[sa * 4096 + (wn + n * 16 + fr) * 32 + kofs];
        #pragma unroll
        for (int m = 0; m < 4; ++m)
            af0[m] = *(const s16x8*)&Asm[sa * 8192 + (wm + m * 16 + fr) * 32 + kofs];
        const int u2 = 2 * v + 4;
        if (u2 < NK) {
            int st = sa + 4; if (st >= 6) st -= 6;
            stage(u2, st);
            int st1 = st + 1; if (st1 >= 6) st1 -= 6;
            stage(u2 + 1, st1);
        }
        __builtin_amdgcn_s_setprio(1);
        #pragma unroll
        for (int m = 0; m < 4; ++m)
            #pragma unroll
            for (int n = 0; n < 4; ++n)
                acc[m][n] = __builtin_amdgcn_mfma_f32_16x16x32_bf16(af0[m], b0[n], acc[m][n], 0, 0, 0);
        __builtin_amdgcn_s_setprio(0);
        s16x8 b1[4], af1[4];
        #pragma unroll
        for (int n = 0; n < 4; ++n)
            b1[n] = *(const s16x8*)&Bsm[sb * 4096 + (wn + n * 16 + fr) * 32 + kofs];
        #pragma unroll
        for (int m = 0; m < 4; ++m)
            af1[m] = *(const s16x8*)&Asm[sb * 8192 + (wm + m * 16 + fr) * 32 + kofs];
        __builtin_amdgcn_s_setprio(1);
        #pragma unroll
        for (int m = 0; m < 4; ++m)
            #pragma unroll
            for (int n = 0; n < 4; ++n)
                acc[m][n] = __builtin_amdgcn_mfma_f32_16x16x32_bf16(af1[m], b1[n], acc[m][n], 0, 0, 0);
        __builtin_amdgcn_s_setprio(0);
        MEMB;
        sa += 2; if (sa >= 6) sa = 0;
    }

    if (MODE == 0) {
        // rows = c, cols = (b,ni); Hts[b][c+1+s(ni)][pi(ni)] = relu(acc+bs[c])
        const int gb = col0 + wn;              // 64-aligned global col base
        const int b  = gb >> 8;
        const int gl = gb & 255;               // 64-aligned ni group base
        const int nib = gl + fr;
        u16* HtsW = auxout + (size_t)b * 514 * 256;
        const int px = gl + 4 * fr;
        const int s0 = shf(nib), s3 = shf(nib + 48);
        #pragma unroll
        for (int m = 0; m < 4; ++m) {
            #pragma unroll
            for (int j = 0; j < 4; ++j) {
                const int c = row0 + wm + m * 16 + q * 4 + j;
                const float bsv = bias[c];
                u16 vv[4];
                #pragma unroll
                for (int n = 0; n < 4; ++n)
                    vv[n] = f2b(fmaxf(acc[m][n][j] + bsv, 0.0f));
                if (s0 == s3) {
                    ushort4 v4 = {vv[0], vv[1], vv[2], vv[3]};
                    *(ushort4*)&HtsW[(size_t)(c + 1 + s0) * 256 + px] = v4;
                } else {
                    #pragma unroll
                    for (int n = 0; n < 4; ++n)
                        HtsW[(size_t)(c + 1 + shf(nib + n * 16)) * 256 + px + n] = vv[n];
                }
            }
        }
    } else if (MODE == 2) {
        #pragma unroll
        for (int m = 0; m < 4; ++m) {
            #pragma unroll
            for (int j = 0; j < 4; ++j) {
                const int row = row0 + wm + m * 16 + q * 4 + j;
                #pragma unroll
                for (int n = 0; n < 4; ++n) {
                    const int col = col0 + wn + n * 16 + fr;
                    ((float*)outv)[(size_t)row * 512 + col] =
                        acc[m][n][j] + bias[col] + res[(size_t)row * 512 + col];
                }
            }
        }
    } else {
        // conv: rows = no, cols = c; Y[b][no][pi(c)]; SEpart per (ct,wn) slot
        const int cb = col0 + wn;              // 64-aligned c group base
        const int px = cb + 4 * fr;
        const int sslot = (col0 >> 7) * 2 + (wn >> 6);   // 0..7
        #pragma unroll
        for (int m = 0; m < 4; ++m) {
            #pragma unroll
            for (int j = 0; j < 4; ++j) {
                const int no = wm + m * 16 + q * 4 + j;
                const float bcv = bias[no];
                float p = 0.0f;
                u16 vv[4];
                #pragma unroll
                for (int n = 0; n < 4; ++n) {
                    float v = acc[m][n][j];
                    vv[n] = f2b(v + bcv);
                    p += v;
                }
                ushort4 v4 = {vv[0], vv[1], vv[2], vv[3]};
                *(ushort4*)&auxout[((size_t)bidx * NN + no) * CCH + px] = v4;
                p += __shfl_xor(p, 1);
                p += __shfl_xor(p, 2);
                p += __shfl_xor(p, 4);
                p += __shfl_xor(p, 8);
                if (fr == 0)
                    SEpart[sslot * 16384 + bidx * NN + no] = p;
            }
        }
    }
}

// ---------------- gemm1: 8-phase 256x256xBK64, semlp fused, pi stores ----------------
__global__ __launch_bounds__(512, 1) void gemm1_8ph(
    const u16* __restrict__ Yb, const u16* __restrict__ Wf1t,
    const float* __restrict__ bf1, u16* __restrict__ T,
    const float* __restrict__ SEpart, const float* __restrict__ bc,
    const float* __restrict__ We1, const float* __restrict__ be1,
    const float* __restrict__ We2, const float* __restrict__ be2)
{
    __shared__ u16 Ab[2][256 * 64];
    __shared__ u16 Bb[2][256 * 64];
    __shared__ float sse[256];
    __shared__ float e1f[32];
    __shared__ float exs[256];

    const int tid = threadIdx.x;
    const int l   = tid & 63;
    const int w   = tid >> 6;
    const int work = (blockIdx.x & 7) * 32 + (blockIdx.x >> 3);
    const int row0 = (work >> 2) * 256;          // = batch * 256
    const int col0 = (work & 3) * 256;

    const u16* Aab = Yb  + (size_t)row0 * 512;
    const u16* Bab = Wf1t + (size_t)col0 * 512;

    const int wm = (w >> 2) * 128;
    const int wn = (w & 3) * 64;
    const int fr = l & 15;
    const int q  = l >> 4;
    const int r7 = fr & 7;

    // ---- fused semlp (vmem retires before staging) ----
    if (tid < 256) {
        int o = row0 + tid;
        float sum = 0.0f;
        #pragma unroll
        for (int i = 0; i < 8; ++i) sum += SEpart[i * 16384 + o];
        sse[tid] = sum * (1.0f / CCH) + bc[tid];
    }
    __syncthreads();
    if (tid < 32) {
        float a = be1[tid];
        #pragma unroll 8
        for (int i = 0; i < 256; ++i) a += sse[i] * We1[i * 32 + tid];
        e1f[tid] = fmaxf(a, 0.0f);
    }
    __syncthreads();
    if (tid < 256) {
        float a = be2[tid];
        #pragma unroll
        for (int j = 0; j < 32; ++j) a += e1f[j] * We2[j * 256 + tid];
        exs[tid] = 1.0f / (1.0f + expf(-a));
    }
    __syncthreads();

    const int strow = tid >> 3;
    const int sslot = tid & 7;
    const int gslot = sslot ^ (strow & 7);
    const size_t goff = (size_t)strow * 512 + gslot * 8;
    const int     loff = strow * 64 + sslot * 8;

    auto stageA = [&](int c, int kt, int j) {
        gll16(Aab + (size_t)(j * 64) * 512 + kt * 64 + goff,
              &Ab[c][j * 64 * 64 + loff]);
    };
    auto stageB = [&](int c, int kt, int j) {
        gll16(Bab + (size_t)(j * 64) * 512 + kt * 64 + goff,
              &Bb[c][j * 64 * 64 + loff]);
    };

    stageA(0, 0, 0); stageA(0, 0, 1); stageA(0, 0, 2); stageA(0, 0, 3);
    stageB(0, 0, 0); stageB(0, 0, 1); stageB(0, 0, 2); stageB(0, 0, 3);
    stageA(1, 1, 0); stageA(1, 1, 2);
    stageB(1, 1, 0); stageB(1, 1, 1); stageB(1, 1, 2); stageB(1, 1, 3);

    const f32x4 zero = {0.0f, 0.0f, 0.0f, 0.0f};
    f32x4 acc[8][4];
    #pragma unroll
    for (int m = 0; m < 8; ++m)
        #pragma unroll
        for (int n = 0; n < 4; ++n) acc[m][n] = zero;

    s16x8 afv[4][2], bfv[4][2];

#define LDA8(c, r, ks) (*(const s16x8*)&Ab[c][(r) * 64 + (((((ks) << 2) + q) ^ r7) << 3)])
#define LDB8(c, r, ks) (*(const s16x8*)&Bb[c][(r) * 64 + (((((ks) << 2) + q) ^ r7) << 3)])

    for (int t = 0; t < 8; ++t) {
        const int c = t & 1;
        // P0
        if (t < 7) { stageA(c ^ 1, t + 1, 1); stageA(c ^ 1, t + 1, 3); VM8; }
        else       { VM0; }
        __builtin_amdgcn_s_barrier();
        MEMB;
        #pragma unroll
        for (int m = 0; m < 4; ++m) {
            afv[m][0] = LDA8(c, wm + m * 16 + fr, 0);
            afv[m][1] = LDA8(c, wm + m * 16 + fr, 1);
        }
        #pragma unroll
        for (int n = 0; n < 2; ++n) {
            bfv[n][0] = LDB8(c, wn + n * 16 + fr, 0);
            bfv[n][1] = LDB8(c, wn + n * 16 + fr, 1);
        }
        LGKM0;
        __builtin_amdgcn_s_setprio(1);
        #pragma unroll
        for (int m = 0; m < 4; ++m)
            #pragma unroll
            for (int n = 0; n < 2; ++n) {
                acc[m][n] = __builtin_amdgcn_mfma_f32_16x16x32_bf16(afv[m][0], bfv[n][0], acc[m][n], 0, 0, 0);
                acc[m][n] = __builtin_amdgcn_mfma_f32_16x16x32_bf16(afv[m][1], bfv[n][1], acc[m][n], 0, 0, 0);
            }
        __builtin_amdgcn_s_setprio(0);
        __builtin_amdgcn_s_barrier();
        // P1
        if (t < 6) { stageA(c, t + 2, 0); stageA(c, t + 2, 2); }
        #pragma unroll
        for (int n = 2; n < 4; ++n) {
            bfv[n][0] = LDB8(c, wn + n * 16 + fr, 0);
            bfv[n][1] = LDB8(c, wn + n * 16 + fr, 1);
        }
        LGKM0;
        __builtin_amdgcn_s_setprio(1);
        #pragma unroll
        for (int m = 0; m < 4; ++m)
            #pragma unroll
            for (int n = 2; n < 4; ++n) {
                acc[m][n] = __builtin_amdgcn_mfma_f32_16x16x32_bf16(afv[m][0], bfv[n][0], acc[m][n], 0, 0, 0);
                acc[m][n] = __builtin_amdgcn_mfma_f32_16x16x32_bf16(afv[m][1], bfv[n][1], acc[m][n], 0, 0, 0);
            }
        __builtin_amdgcn_s_setprio(0);
        __builtin_amdgcn_s_barrier();
        // P2
        if (t < 6) { stageB(c, t + 2, 0); stageB(c, t + 2, 1); }
        #pragma unroll
        for (int m = 0; m < 4; ++m) {
            afv[m][0] = LDA8(c, wm + 64 + m * 16 + fr, 0);
            afv[m][1] = LDA8(c, wm + 64 + m * 16 + fr, 1);
        }
        LGKM0;
        __builtin_amdgcn_s_setprio(1);
        #pragma unroll
        for (int m = 0; m < 4; ++m)
            #pragma unroll
            for (int n = 0; n < 2; ++n) {
                acc[4 + m][n] = __builtin_amdgcn_mfma_f32_16x16x32_bf16(afv[m][0], bfv[n][0], acc[4 + m][n], 0, 0, 0);
                acc[4 + m][n] = __builtin_amdgcn_mfma_f32_16x16x32_bf16(afv[m][1], bfv[n][1], acc[4 + m][n], 0, 0, 0);
            }
        __builtin_amdgcn_s_setprio(0);
        __builtin_amdgcn_s_barrier();
        // P3
        if (t < 6) { stageB(c, t + 2, 2); stageB(c, t + 2, 3); }
        __builtin_amdgcn_s_setprio(1);
        #pragma unroll
        for (int m = 0; m < 4; ++m)
            #pragma unroll
            for (int n = 2; n < 4; ++n) {
                acc[4 + m][n] = __builtin_amdgcn_mfma_f32_16x16x32_bf16(afv[m][0], bfv[n][0], acc[4 + m][n], 0, 0, 0);
                acc[4 + m][n] = __builtin_amdgcn_mfma_f32_16x16x32_bf16(afv[m][1], bfv[n][1], acc[4 + m][n], 0, 0, 0);
            }
        __builtin_amdgcn_s_setprio(0);
        __builtin_amdgcn_s_barrier();
    }

    // ---- epilogue: pi-permuted ushort4 stores ----
    const int cgb = col0 + wn;                 // 64-aligned col group base
    float bval[4];
    #pragma unroll
    for (int n = 0; n < 4; ++n) bval[n] = bf1[cgb + n * 16 + fr];
    #pragma unroll
    for (int m = 0; m < 8; ++m) {
        #pragma unroll
        for (int j = 0; j < 4; ++j) {
            const int rl  = wm + m * 16 + q * 4 + j;
            const int row = row0 + rl;
            const float sc = exs[rl];
            u16 vv[4];
            #pragma unroll
            for (int n = 0; n < 4; ++n)
                vv[n] = f2b(fmaxf(acc[m][n][j] * sc + bval[n], 0.0f));
            ushort4 v4 = {vv[0], vv[1], vv[2], vv[3]};
            *(ushort4*)&T[(size_t)row * 1024 + cgb + 4 * fr] = v4;
        }
    }
#undef LDA8
#undef LDB8
}

extern "C" void kernel_launch(void* const* d_in, const int* in_sizes, int n_in,
                              void* d_out, int out_size, void* d_ws, size_t ws_size,
                              hipStream_t stream) {
    const float* x    = (const float*)d_in[0];
    const float* ln_g = (const float*)d_in[1];
    const float* ln_b = (const float*)d_in[2];
    const float* Ws   = (const float*)d_in[3];
    const float* bs   = (const float*)d_in[4];
    const float* Wc   = (const float*)d_in[5];
    const float* bc   = (const float*)d_in[6];
    const float* We1  = (const float*)d_in[7];
    const float* be1  = (const float*)d_in[8];
    const float* We2  = (const float*)d_in[9];
    const float* be2  = (const float*)d_in[10];
    const float* Wf1  = (const float*)d_in[11];
    const float* bf1  = (const float*)d_in[12];
    const float* Wf2  = (const float*)d_in[13];
    const float* bf2  = (const float*)d_in[14];
    float* out = (float*)d_out;
    char* w8   = (char*)d_ws;

    u16* XN  = (u16*)(w8);
    u16* Y   = XN;
    u16* Hts = (u16*)(w8 + (16u << 20));
    u16* T   = (u16*)(w8 + (16u << 20));
    char* tail = w8 + 50397184;
    float* SEpart = (float*)(tail);                 // 512K [8][64][256]
    u16* Wst      = (u16*)(tail + 524288);          // 512K [512][512]
    u16* Wf1t     = (u16*)(tail + 1048576);         // 1M   [1024][512-perm]
    u16* Wf2t     = (u16*)(tail + 2097152);         // 1M   [512][1024-perm]
    u16* Wc3      = (u16*)(tail + 3145728);         // 384K [3][256][256-perm]

    prep_ln_kernel<<<6400, 256, 0, stream>>>(Ws, Wst, Wf1, Wf1t, Wf2, Wf2t,
                                             Wc, Wc3, Hts, x, ln_g, ln_b, XN);
    // Hts = shifted-transpose(relu(Ws^T-rows @ XN-rows + bs)), ni pi-permuted
    gemm_pipe<0><<<256, 512, 0, stream>>>(Wst, XN, bs, nullptr,
                                          nullptr, Hts, nullptr);
    // Y = conv1d(shift(H)) + bc (c pi-permuted); SEpart partial row-sums
    gemm_pipe<3><<<256, 512, 0, stream>>>(Wc3, Hts, bc, nullptr,
                                          nullptr, Y, SEpart);
    // T = relu((Y*ex) @ Wf1 + bf1), col pi-permuted [8-phase; semlp fused]
    gemm1_8ph<<<256, 512, 0, stream>>>(Y, Wf1t, bf1, T, SEpart, bc,
                                       We1, be1, We2, be2);
    // out = T @ Wf2 + bf2 + x
    gemm_pipe<2><<<256, 512, 0, stream>>>(T, Wf2t, bf2, x,
                                          out, nullptr, nullptr);
}